// Round 3
// baseline (1431.609 us; speedup 1.0000x reference)
//
#include <hip/hip_runtime.h>
#include <hip/hip_bf16.h>

// MLA transformer block on MI355X. Round 3: attention restructured --
// causal pair-scheduling (q-tiles i & 31-i per block), Q in registers,
// shared K/V fragment reads for both q-tiles, 62.5KB LDS -> 2 blocks/CU.

typedef short bf16x8 __attribute__((ext_vector_type(8)));
typedef float f32x4 __attribute__((ext_vector_type(4)));
typedef unsigned short u16;

#define BM 128
#define BN 128
#define BK 32

__device__ __forceinline__ u16 f2bf(float f) {
  unsigned int u = __builtin_bit_cast(unsigned int, f);
  u += 0x7FFFu + ((u >> 16) & 1u);
  return (u16)(u >> 16);
}

__device__ __forceinline__ void gload_lds16(const void* g, void* l) {
  __builtin_amdgcn_global_load_lds(
      (const __attribute__((address_space(1))) unsigned int*)(uintptr_t)g,
      (__attribute__((address_space(3))) unsigned int*)(unsigned int)(uintptr_t)l,
      16, 0, 0);
}

// ---------------- transpose + f32->bf16 : out[N][K] = (bf16) in[K][N] ------
__global__ __launch_bounds__(256) void k_transpose_bf16(
    const float* __restrict__ in, u16* __restrict__ out, int K, int N) {
  __shared__ float tile[32][33];
  int k0 = blockIdx.x * 32, n0 = blockIdx.y * 32;
  int tx = threadIdx.x & 31, ty = threadIdx.x >> 5;
#pragma unroll
  for (int i = 0; i < 4; ++i) {
    int k = k0 + ty + i * 8, n = n0 + tx;
    tile[ty + i * 8][tx] = (k < K && n < N) ? in[(size_t)k * N + n] : 0.f;
  }
  __syncthreads();
#pragma unroll
  for (int i = 0; i < 4; ++i) {
    int n = n0 + ty + i * 8, k = k0 + tx;
    if (n < N && k < K) out[(size_t)n * K + k] = f2bf(tile[tx][ty + i * 8]);
  }
}

// ---------------- RoPE tables: cos/sin[s][i], i<32 -------------------------
__global__ void k_rope_table(float* __restrict__ cosT, float* __restrict__ sinT) {
  int idx = blockIdx.x * 256 + threadIdx.x;
  if (idx >= 2048 * 32) return;
  int s = idx >> 5, i = idx & 31;
  float inv = exp2f(-(float)i * 0.41524101186092037f); // log2(10000)/32
  float a = (float)s * inv;
  cosT[idx] = cosf(a);
  sinT[idx] = sinf(a);
}

// ---------------- LayerNorm row=2048, out bf16 -----------------------------
__global__ __launch_bounds__(256) void k_ln(const float* __restrict__ x,
                                            const float* __restrict__ w,
                                            const float* __restrict__ b,
                                            u16* __restrict__ out) {
  const int row = blockIdx.x, tid = threadIdx.x;
  const float* xr = x + (size_t)row * 2048;
  float xv[8];
  *(float4*)&xv[0] = ((const float4*)xr)[tid * 2];
  *(float4*)&xv[4] = ((const float4*)xr)[tid * 2 + 1];
  float s = 0.f, ss = 0.f;
#pragma unroll
  for (int j = 0; j < 8; ++j) { s += xv[j]; ss += xv[j] * xv[j]; }
#pragma unroll
  for (int m_ = 32; m_; m_ >>= 1) { s += __shfl_xor(s, m_); ss += __shfl_xor(ss, m_); }
  __shared__ float red[8];
  const int wv = tid >> 6;
  if ((tid & 63) == 0) { red[wv] = s; red[wv + 4] = ss; }
  __syncthreads();
  s = red[0] + red[1] + red[2] + red[3];
  ss = red[4] + red[5] + red[6] + red[7];
  const float mean = s * (1.f / 2048.f);
  const float rs = rsqrtf(ss * (1.f / 2048.f) - mean * mean + 1e-5f);
  float wv8[8], bv8[8];
  *(float4*)&wv8[0] = ((const float4*)w)[tid * 2];
  *(float4*)&wv8[4] = ((const float4*)w)[tid * 2 + 1];
  *(float4*)&bv8[0] = ((const float4*)b)[tid * 2];
  *(float4*)&bv8[4] = ((const float4*)b)[tid * 2 + 1];
  u16 t[8] __attribute__((aligned(16)));
#pragma unroll
  for (int j = 0; j < 8; ++j) t[j] = f2bf((xv[j] - mean) * rs * wv8[j] + bv8[j]);
  *(int4*)&out[(size_t)row * 2048 + tid * 8] = *(int4*)t;
}

// ---------------- RoPE in-place (fp32) -------------------------------------
__global__ void k_rope_q(float* __restrict__ qr, const float* __restrict__ cosT,
                         const float* __restrict__ sinT) {
  int idx = blockIdx.x * 256 + threadIdx.x; // 4096*16*32
  if (idx >= 4096 * 16 * 32) return;
  int i = idx & 31, rest = idx >> 5;
  int h = rest & 15, m = rest >> 4;
  int s = m & 2047;
  float c = cosT[s * 32 + i], sn = sinT[s * 32 + i];
  float* p = qr + (size_t)m * 1024 + h * 64 + i;
  float x0 = p[0], x1 = p[32];
  p[0] = x0 * c - x1 * sn;
  p[32] = x1 * c + x0 * sn;
}

__global__ void k_rope_k(float* __restrict__ kr, const float* __restrict__ cosT,
                         const float* __restrict__ sinT, float* __restrict__ nkv) {
  int idx = blockIdx.x * 256 + threadIdx.x; // 4096*32
  if (idx >= 4096 * 32) return;
  int i = idx & 31, m = idx >> 5;
  int s = m & 2047;
  float c = cosT[s * 32 + i], sn = sinT[s * 32 + i];
  float* p = kr + (size_t)m * 64 + i;
  float x0 = p[0], x1 = p[32];
  float y0 = x0 * c - x1 * sn;
  float y1 = x1 * c + x0 * sn;
  p[0] = y0; p[32] = y1;
  nkv[(size_t)m * 576 + 512 + i] = y0;
  nkv[(size_t)m * 576 + 544 + i] = y1;
}

// ---------------- GEMM: C[M][N] = A[M][K](bf16) * Bt[N][K]^T + bias --------
enum { EP_Q = 0, EP_DKV = 1, EP_KV = 2, EP_RES = 3, EP_GELU = 4 };

template <int EP>
__global__ __launch_bounds__(256) void k_gemm(
    const u16* __restrict__ A, const u16* __restrict__ Bt,
    const float* __restrict__ bias, int K, int Nreal,
    void* out0_, void* out1_, void* out2_, const float* __restrict__ res) {
  __shared__ u16 As[BM * BK];
  __shared__ u16 Bs[BN * BK];
  const int tid = threadIdx.x;
  const int w = tid >> 6, lane = tid & 63;
  const int bm = blockIdx.y * BM, bn = blockIdx.x * BN;
  const int wr = (w >> 1) * 64, wc = (w & 1) * 64;

  const u16* Ag = A + (size_t)(bm + w * 32 + (lane >> 2)) * K + (lane & 3) * 8;
  const u16* Bg = Bt + (size_t)(bn + w * 32 + (lane >> 2)) * K + (lane & 3) * 8;
  char* lA = (char*)As + w * 2048;
  char* lB = (char*)Bs + w * 2048;

  f32x4 acc[4][4] = {};
  for (int k0 = 0; k0 < K; k0 += BK) {
    __syncthreads();
    gload_lds16(Ag, lA);
    gload_lds16(Ag + 16 * K, lA + 1024);
    gload_lds16(Bg, lB);
    gload_lds16(Bg + 16 * K, lB + 1024);
    Ag += BK; Bg += BK;
    __syncthreads();
    const int ka = (lane >> 4) * 8;
    const int lc = lane & 15;
    bf16x8 av[4], bv[4];
#pragma unroll
    for (int i = 0; i < 4; ++i) av[i] = *(const bf16x8*)&As[(wr + i * 16 + lc) * BK + ka];
#pragma unroll
    for (int j = 0; j < 4; ++j) bv[j] = *(const bf16x8*)&Bs[(wc + j * 16 + lc) * BK + ka];
#pragma unroll
    for (int i = 0; i < 4; ++i)
#pragma unroll
      for (int j = 0; j < 4; ++j)
        acc[i][j] = __builtin_amdgcn_mfma_f32_16x16x32_bf16(av[i], bv[j], acc[i][j], 0, 0, 0);
  }

  const int lr = (lane >> 4) * 4, lc = lane & 15;
#pragma unroll
  for (int i = 0; i < 4; ++i) {
#pragma unroll
    for (int j = 0; j < 4; ++j) {
      int col = bn + wc + j * 16 + lc;
      if (col >= Nreal) continue;
      float bb = bias ? bias[col] : 0.f;
#pragma unroll
      for (int r = 0; r < 4; ++r) {
        int row = bm + wr + i * 16 + lr + r;
        float c = acc[i][j][r] + bb;
        if constexpr (EP == EP_Q) {
          u16* qn = (u16*)out0_; float* qr = (float*)out1_;
          int hh = col / 192, d = col - hh * 192;
          if (d < 128) qn[(size_t)row * 2048 + hh * 128 + d] = f2bf(c);
          else qr[(size_t)row * 1024 + hh * 64 + (d - 128)] = c;
        } else if constexpr (EP == EP_DKV) {
          u16* ckv = (u16*)out0_; float* nkv = (float*)out1_; float* kr = (float*)out2_;
          if (col < 512) { ckv[(size_t)row * 512 + col] = f2bf(c); nkv[(size_t)row * 576 + col] = c; }
          else kr[(size_t)row * 64 + (col - 512)] = c;
        } else if constexpr (EP == EP_KV) {
          u16* kn = (u16*)out0_; u16* vv = (u16*)out1_;
          int hh = col >> 8, d = col & 255;
          if (d < 128) kn[(size_t)row * 2048 + hh * 128 + d] = f2bf(c);
          else vv[(size_t)row * 2048 + hh * 128 + (d - 128)] = f2bf(c);
        } else if constexpr (EP == EP_RES) {
          float* out = (float*)out0_;
          out[(size_t)row * Nreal + col] = res[(size_t)row * Nreal + col] + c;
        } else { // EP_GELU
          u16* g = (u16*)out0_;
          float gl = 0.5f * c * (1.f + erff(c * 0.70710678118f));
          g[(size_t)row * Nreal + col] = f2bf(gl);
        }
      }
    }
  }
}

// ---------------- Flash attention, causal-paired ---------------------------
// grid (16 pairs, B*H). Block handles q-tiles qtA=i and qtB=31-i (64 rows
// each): per-block tile-consumptions = 33 (balanced). Q in registers.
// K/V staged once per kv-tile, fragments shared between both q-tiles.
#define QKS 200
#define VPS 72
__global__ __launch_bounds__(256) void k_attn(
    const u16* __restrict__ qn, const float* __restrict__ qr,
    const u16* __restrict__ kn, const float* __restrict__ kr,
    const u16* __restrict__ v, u16* __restrict__ o) {
  __shared__ u16 Ks[64 * QKS];
  __shared__ u16 Vt[128 * VPS];
  __shared__ u16 PsA[64 * VPS];
  __shared__ u16 PsB[64 * VPS];
  const int qtA = blockIdx.x;            // 0..15 (longest kv range first)
  const int qtB = 31 - qtA;              // 16..31
  const int b = blockIdx.y >> 4, h = blockIdx.y & 15;
  const int tid = threadIdx.x, w = tid >> 6, lane = tid & 63;
  const size_t mb = (size_t)b * 2048;
  const float sc2 = 0.07216878365f * 1.4426950408f; // 1/sqrt(192) * log2(e)
  const int lr = (lane >> 4) * 4, lc = lane & 15, ka = (lane >> 4) * 8;

  // ---- Q fragments in registers (per wave: rows w*16+lc of each tile) ----
  bf16x8 qfA[6], qfB[6];
  {
    size_t mA = mb + (size_t)qtA * 64 + w * 16 + lc;
    size_t mB = mb + (size_t)qtB * 64 + w * 16 + lc;
#pragma unroll
    for (int ks = 0; ks < 4; ++ks) {
      qfA[ks] = *(const bf16x8*)&qn[mA * 2048 + h * 128 + ks * 32 + ka];
      qfB[ks] = *(const bf16x8*)&qn[mB * 2048 + h * 128 + ks * 32 + ka];
    }
#pragma unroll
    for (int ks = 0; ks < 2; ++ks) {
      const float* sA = &qr[mA * 1024 + h * 64 + ks * 32 + ka];
      const float* sB = &qr[mB * 1024 + h * 64 + ks * 32 + ka];
      u16 tA[8] __attribute__((aligned(16))), tB[8] __attribute__((aligned(16)));
#pragma unroll
      for (int j = 0; j < 8; ++j) { tA[j] = f2bf(sA[j]); tB[j] = f2bf(sB[j]); }
      qfA[4 + ks] = *(bf16x8*)tA;
      qfB[4 + ks] = *(bf16x8*)tB;
    }
  }

  float mA2[4] = {-1e30f, -1e30f, -1e30f, -1e30f};
  float lA2[4] = {0.f, 0.f, 0.f, 0.f};
  float mB2[4] = {-1e30f, -1e30f, -1e30f, -1e30f};
  float lB2[4] = {0.f, 0.f, 0.f, 0.f};
  f32x4 ofA[8] = {};
  f32x4 ofB[8] = {};

  for (int t = 0; t <= qtB; ++t) {
    const bool doA = (t <= qtA);
    __syncthreads();
    // ---- stage K (bf16 kn + converted kr) ----
    for (int idx = tid; idx < 64 * 24; idx += 256) {
      int r = idx / 24, c = idx - (idx / 24) * 24;
      size_t m = mb + (size_t)t * 64 + r;
      if (c < 16) {
        *(int4*)&Ks[r * QKS + c * 8] = *(const int4*)&kn[m * 2048 + h * 128 + c * 8];
      } else {
        const float* s = &kr[m * 64 + (c - 16) * 8];
        u16 tt[8] __attribute__((aligned(16)));
#pragma unroll
        for (int j = 0; j < 8; ++j) tt[j] = f2bf(s[j]);
        *(int4*)&Ks[r * QKS + c * 8] = *(int4*)tt;
      }
    }
    // ---- stage V transposed ----
    for (int idx = tid; idx < 1024; idx += 256) {
      int d = idx & 127, rb = idx >> 7;
      const u16* vp = &v[(mb + (size_t)t * 64 + rb * 8) * 2048 + h * 128 + d];
      u16 t8[8] __attribute__((aligned(16)));
#pragma unroll
      for (int j = 0; j < 8; ++j) t8[j] = vp[j * 2048];
      *(int4*)&Vt[d * VPS + rb * 8] = *(int4*)t8;
    }
    __syncthreads();

    // ---- QK^T for both tiles, K fragments shared ----
    f32x4 sfA[4] = {};
    f32x4 sfB[4] = {};
#pragma unroll
    for (int j = 0; j < 4; ++j) {
      bf16x8 kf[6];
#pragma unroll
      for (int ks = 0; ks < 6; ++ks)
        kf[ks] = *(const bf16x8*)&Ks[(j * 16 + lc) * QKS + ks * 32 + ka];
      if (doA) {
#pragma unroll
        for (int ks = 0; ks < 6; ++ks)
          sfA[j] = __builtin_amdgcn_mfma_f32_16x16x32_bf16(qfA[ks], kf[ks], sfA[j], 0, 0, 0);
      }
#pragma unroll
      for (int ks = 0; ks < 6; ++ks)
        sfB[j] = __builtin_amdgcn_mfma_f32_16x16x32_bf16(qfB[ks], kf[ks], sfB[j], 0, 0, 0);
    }

    // ---- softmax A ----
    if (doA) {
      float rm[4], fpr[4], ps[4];
#pragma unroll
      for (int j = 0; j < 4; ++j)
#pragma unroll
        for (int r = 0; r < 4; ++r) {
          float x_ = sfA[j][r] * sc2;
          if (t == qtA) {
            int colg = t * 64 + j * 16 + lc;
            int rowg = qtA * 64 + w * 16 + lr + r;
            if (colg > rowg) x_ = -1e30f;
          }
          sfA[j][r] = x_;
        }
#pragma unroll
      for (int r = 0; r < 4; ++r)
        rm[r] = fmaxf(fmaxf(sfA[0][r], sfA[1][r]), fmaxf(sfA[2][r], sfA[3][r]));
#pragma unroll
      for (int msk = 1; msk < 16; msk <<= 1)
#pragma unroll
        for (int r = 0; r < 4; ++r) rm[r] = fmaxf(rm[r], __shfl_xor(rm[r], msk));
#pragma unroll
      for (int r = 0; r < 4; ++r) {
        float mn = fmaxf(mA2[r], rm[r]);
        fpr[r] = exp2f(mA2[r] - mn);
        mA2[r] = mn;
        ps[r] = 0.f;
      }
#pragma unroll
      for (int j = 0; j < 4; ++j)
#pragma unroll
        for (int r = 0; r < 4; ++r) {
          float p = exp2f(sfA[j][r] - mA2[r]);
          ps[r] += p;
          PsA[(w * 16 + lr + r) * VPS + j * 16 + lc] = f2bf(p);
        }
#pragma unroll
      for (int msk = 1; msk < 16; msk <<= 1)
#pragma unroll
        for (int r = 0; r < 4; ++r) ps[r] += __shfl_xor(ps[r], msk);
#pragma unroll
      for (int r = 0; r < 4; ++r) lA2[r] = lA2[r] * fpr[r] + ps[r];
#pragma unroll
      for (int nb = 0; nb < 8; ++nb)
#pragma unroll
        for (int r = 0; r < 4; ++r) ofA[nb][r] *= fpr[r];
    }

    // ---- softmax B ----
    {
      float rm[4], fpr[4], ps[4];
#pragma unroll
      for (int j = 0; j < 4; ++j)
#pragma unroll
        for (int r = 0; r < 4; ++r) {
          float x_ = sfB[j][r] * sc2;
          if (t == qtB) {
            int colg = t * 64 + j * 16 + lc;
            int rowg = qtB * 64 + w * 16 + lr + r;
            if (colg > rowg) x_ = -1e30f;
          }
          sfB[j][r] = x_;
        }
#pragma unroll
      for (int r = 0; r < 4; ++r)
        rm[r] = fmaxf(fmaxf(sfB[0][r], sfB[1][r]), fmaxf(sfB[2][r], sfB[3][r]));
#pragma unroll
      for (int msk = 1; msk < 16; msk <<= 1)
#pragma unroll
        for (int r = 0; r < 4; ++r) rm[r] = fmaxf(rm[r], __shfl_xor(rm[r], msk));
#pragma unroll
      for (int r = 0; r < 4; ++r) {
        float mn = fmaxf(mB2[r], rm[r]);
        fpr[r] = exp2f(mB2[r] - mn);
        mB2[r] = mn;
        ps[r] = 0.f;
      }
#pragma unroll
      for (int j = 0; j < 4; ++j)
#pragma unroll
        for (int r = 0; r < 4; ++r) {
          float p = exp2f(sfB[j][r] - mB2[r]);
          ps[r] += p;
          PsB[(w * 16 + lr + r) * VPS + j * 16 + lc] = f2bf(p);
        }
#pragma unroll
      for (int msk = 1; msk < 16; msk <<= 1)
#pragma unroll
        for (int r = 0; r < 4; ++r) ps[r] += __shfl_xor(ps[r], msk);
#pragma unroll
      for (int r = 0; r < 4; ++r) lB2[r] = lB2[r] * fpr[r] + ps[r];
#pragma unroll
      for (int nb = 0; nb < 8; ++nb)
#pragma unroll
        for (int r = 0; r < 4; ++r) ofB[nb][r] *= fpr[r];
    }

    // Ps written/read by same wave only -- lgkm drain, no barrier needed.
    asm volatile("s_waitcnt lgkmcnt(0)" ::: "memory");

    // ---- PV for both tiles, V fragments shared ----
#pragma unroll
    for (int ks = 0; ks < 2; ++ks) {
      bf16x8 apA = *(const bf16x8*)&PsA[(w * 16 + lc) * VPS + ks * 32 + ka];
      bf16x8 apB = *(const bf16x8*)&PsB[(w * 16 + lc) * VPS + ks * 32 + ka];
#pragma unroll
      for (int nb = 0; nb < 8; ++nb) {
        bf16x8 bvv = *(const bf16x8*)&Vt[(nb * 16 + lc) * VPS + ks * 32 + ka];
        if (doA)
          ofA[nb] = __builtin_amdgcn_mfma_f32_16x16x32_bf16(apA, bvv, ofA[nb], 0, 0, 0);
        ofB[nb] = __builtin_amdgcn_mfma_f32_16x16x32_bf16(apB, bvv, ofB[nb], 0, 0, 0);
      }
    }
  }

#pragma unroll
  for (int r = 0; r < 4; ++r) {
    float invA = 1.f / lA2[r];
    float invB = 1.f / lB2[r];
    size_t mA = mb + (size_t)qtA * 64 + w * 16 + lr + r;
    size_t mB = mb + (size_t)qtB * 64 + w * 16 + lr + r;
#pragma unroll
    for (int nb = 0; nb < 8; ++nb) {
      o[mA * 2048 + h * 128 + nb * 16 + lc] = f2bf(ofA[nb][r] * invA);
      o[mB * 2048 + h * 128 + nb * 16 + lc] = f2bf(ofB[nb][r] * invB);
    }
  }
}

// ---------------- launch ----------------------------------------------------
extern "C" void kernel_launch(void* const* d_in, const int* in_sizes, int n_in,
                              void* d_out, int out_size, void* d_ws, size_t ws_size,
                              hipStream_t stream) {
  const float* x = (const float*)d_in[0];
  const float* ln1w = (const float*)d_in[1];
  const float* ln1b = (const float*)d_in[2];
  const float* ln2w = (const float*)d_in[3];
  const float* ln2b = (const float*)d_in[4];
  const float* wq = (const float*)d_in[5];
  const float* bq = (const float*)d_in[6];
  const float* wdkv = (const float*)d_in[7];
  const float* bdkv = (const float*)d_in[8];
  const float* wkv = (const float*)d_in[9];
  const float* bkv = (const float*)d_in[10];
  const float* wo = (const float*)d_in[11];
  const float* bo = (const float*)d_in[12];
  const float* w1 = (const float*)d_in[13];
  const float* b1 = (const float*)d_in[14];
  const float* w2 = (const float*)d_in[15];
  const float* b2 = (const float*)d_in[16];
  (void)in_sizes; (void)n_in; (void)out_size; (void)ws_size;

  char* ws = (char*)d_ws;
  size_t off = 0;
  auto alloc = [&](size_t bytes) { void* p = ws + off; off += (bytes + 255) & ~(size_t)255; return p; };

  u16* wqT = (u16*)alloc(3072ull * 2048 * 2);
  u16* wdkvT = (u16*)alloc(640ull * 2048 * 2);   // 576 real rows, padded to 640
  u16* wkvT = (u16*)alloc(4096ull * 512 * 2);
  u16* woT = (u16*)alloc(2048ull * 2048 * 2);
  u16* w1T = (u16*)alloc(8192ull * 2048 * 2);
  u16* w2T = (u16*)alloc(2048ull * 8192 * 2);
  u16* hbuf = (u16*)alloc(4096ull * 2048 * 2);   // LN1 out; reused for LN2 out
  float* cosT = (float*)alloc(2048ull * 32 * 4);
  float* sinT = (float*)alloc(2048ull * 32 * 4);
  u16* obuf = (u16*)alloc(4096ull * 2048 * 2);
  char* G0 = ws + off;                           // FFN g overlays the region below
  u16* qnb = (u16*)alloc(4096ull * 2048 * 2);
  float* qrb = (float*)alloc(4096ull * 1024 * 4);
  u16* ckvb = (u16*)alloc(4096ull * 512 * 2);
  float* krb = (float*)alloc(4096ull * 64 * 4);
  u16* knb = (u16*)alloc(4096ull * 2048 * 2);
  u16* vb = (u16*)alloc(4096ull * 2048 * 2);
  u16* gb = (u16*)G0;                            // 67.1MB <= 72.3MB region

  float* xout = (float*)d_out;                   // [4096][2048]
  float* nkv = xout + 4096ull * 2048;            // [4096][576]

  dim3 blk(256);
  k_transpose_bf16<<<dim3(64, 96), blk, 0, stream>>>(wq, wqT, 2048, 3072);
  k_transpose_bf16<<<dim3(64, 18), blk, 0, stream>>>(wdkv, wdkvT, 2048, 576);
  k_transpose_bf16<<<dim3(16, 128), blk, 0, stream>>>(wkv, wkvT, 512, 4096);
  k_transpose_bf16<<<dim3(64, 64), blk, 0, stream>>>(wo, woT, 2048, 2048);
  k_transpose_bf16<<<dim3(64, 256), blk, 0, stream>>>(w1, w1T, 2048, 8192);
  k_transpose_bf16<<<dim3(256, 64), blk, 0, stream>>>(w2, w2T, 8192, 2048);
  k_rope_table<<<dim3(256), blk, 0, stream>>>(cosT, sinT);
  k_ln<<<dim3(4096), blk, 0, stream>>>(x, ln1w, ln1b, hbuf);
  k_gemm<EP_Q><<<dim3(24, 32), blk, 0, stream>>>(hbuf, wqT, bq, 2048, 3072, qnb, qrb, nullptr, nullptr);
  k_gemm<EP_DKV><<<dim3(5, 32), blk, 0, stream>>>(hbuf, wdkvT, bdkv, 2048, 576, ckvb, nkv, krb, nullptr);
  k_rope_q<<<dim3(8192), blk, 0, stream>>>(qrb, cosT, sinT);
  k_rope_k<<<dim3(512), blk, 0, stream>>>(krb, cosT, sinT, nkv);
  k_gemm<EP_KV><<<dim3(32, 32), blk, 0, stream>>>(ckvb, wkvT, bkv, 512, 4096, knb, vb, nullptr, nullptr);
  k_attn<<<dim3(16, 32), blk, 0, stream>>>(qnb, qrb, knb, krb, vb, obuf);
  k_gemm<EP_RES><<<dim3(16, 32), blk, 0, stream>>>(obuf, woT, bo, 2048, 2048, xout, nullptr, nullptr, x);
  k_ln<<<dim3(4096), blk, 0, stream>>>(xout, ln2w, ln2b, hbuf);
  k_gemm<EP_GELU><<<dim3(64, 32), blk, 0, stream>>>(hbuf, w1T, b1, 2048, 8192, gb, nullptr, nullptr, nullptr);
  k_gemm<EP_RES><<<dim3(16, 32), blk, 0, stream>>>(gb, w2T, b2, 8192, 2048, xout, nullptr, nullptr, xout);
}

// Round 4
// 1207.100 us; speedup vs baseline: 1.1860x; 1.1860x over previous
//
#include <hip/hip_runtime.h>
#include <hip/hip_bf16.h>

// MLA transformer block on MI355X. Round 4: attention re-pipelined.
// Pre-packed bf16 operand buffers (qall/knb2h/krb_bf/vbT) so the attn loop
// stages with pure int4 copies; register prefetch of tile t+1 overlapped with
// compute of tile t; raw s_barrier (no vmcnt drain); 53KB LDS -> 3 blocks/CU.

typedef short bf16x8 __attribute__((ext_vector_type(8)));
typedef float f32x4 __attribute__((ext_vector_type(4)));
typedef unsigned short u16;

#define BM 128
#define BN 128
#define BK 32

__device__ __forceinline__ u16 f2bf(float f) {
  unsigned int u = __builtin_bit_cast(unsigned int, f);
  u += 0x7FFFu + ((u >> 16) & 1u);
  return (u16)(u >> 16);
}

__device__ __forceinline__ void gload_lds16(const void* g, void* l) {
  __builtin_amdgcn_global_load_lds(
      (const __attribute__((address_space(1))) unsigned int*)(uintptr_t)g,
      (__attribute__((address_space(3))) unsigned int*)(unsigned int)(uintptr_t)l,
      16, 0, 0);
}

// ---------------- transpose + f32->bf16 : out[N][K] = (bf16) in[K][N] ------
__global__ __launch_bounds__(256) void k_transpose_bf16(
    const float* __restrict__ in, u16* __restrict__ out, int K, int N) {
  __shared__ float tile[32][33];
  int k0 = blockIdx.x * 32, n0 = blockIdx.y * 32;
  int tx = threadIdx.x & 31, ty = threadIdx.x >> 5;
#pragma unroll
  for (int i = 0; i < 4; ++i) {
    int k = k0 + ty + i * 8, n = n0 + tx;
    tile[ty + i * 8][tx] = (k < K && n < N) ? in[(size_t)k * N + n] : 0.f;
  }
  __syncthreads();
#pragma unroll
  for (int i = 0; i < 4; ++i) {
    int n = n0 + ty + i * 8, k = k0 + tx;
    if (n < N && k < K) out[(size_t)n * K + k] = f2bf(tile[tx][ty + i * 8]);
  }
}

// ---------------- V transpose per (b,h): vb[m][h*128+d] -> vbT[bh][d][s] ----
__global__ __launch_bounds__(256) void k_transpose_v(
    const u16* __restrict__ vb, u16* __restrict__ vbT) {
  __shared__ u16 tile[32][34];
  int bh = blockIdx.z, b = bh >> 4, h = bh & 15;
  int s0 = blockIdx.x * 32, d0 = blockIdx.y * 32;
  int tx = threadIdx.x & 31, ty = threadIdx.x >> 5;
#pragma unroll
  for (int i = 0; i < 4; ++i)
    tile[ty + i * 8][tx] =
        vb[((size_t)b * 2048 + s0 + ty + i * 8) * 2048 + h * 128 + d0 + tx];
  __syncthreads();
#pragma unroll
  for (int i = 0; i < 4; ++i)
    vbT[((size_t)bh * 128 + d0 + ty + i * 8) * 2048 + s0 + tx] = tile[tx][ty + i * 8];
}

// ---------------- RoPE tables: cos/sin[s][i], i<32 -------------------------
__global__ void k_rope_table(float* __restrict__ cosT, float* __restrict__ sinT) {
  int idx = blockIdx.x * 256 + threadIdx.x;
  if (idx >= 2048 * 32) return;
  int s = idx >> 5, i = idx & 31;
  float inv = exp2f(-(float)i * 0.41524101186092037f); // log2(10000)/32
  float a = (float)s * inv;
  cosT[idx] = cosf(a);
  sinT[idx] = sinf(a);
}

// ---------------- LayerNorm row=2048, out bf16 -----------------------------
__global__ __launch_bounds__(256) void k_ln(const float* __restrict__ x,
                                            const float* __restrict__ w,
                                            const float* __restrict__ b,
                                            u16* __restrict__ out) {
  const int row = blockIdx.x, tid = threadIdx.x;
  const float* xr = x + (size_t)row * 2048;
  float xv[8];
  *(float4*)&xv[0] = ((const float4*)xr)[tid * 2];
  *(float4*)&xv[4] = ((const float4*)xr)[tid * 2 + 1];
  float s = 0.f, ss = 0.f;
#pragma unroll
  for (int j = 0; j < 8; ++j) { s += xv[j]; ss += xv[j] * xv[j]; }
#pragma unroll
  for (int m_ = 32; m_; m_ >>= 1) { s += __shfl_xor(s, m_); ss += __shfl_xor(ss, m_); }
  __shared__ float red[8];
  const int wv = tid >> 6;
  if ((tid & 63) == 0) { red[wv] = s; red[wv + 4] = ss; }
  __syncthreads();
  s = red[0] + red[1] + red[2] + red[3];
  ss = red[4] + red[5] + red[6] + red[7];
  const float mean = s * (1.f / 2048.f);
  const float rs = rsqrtf(ss * (1.f / 2048.f) - mean * mean + 1e-5f);
  float wv8[8], bv8[8];
  *(float4*)&wv8[0] = ((const float4*)w)[tid * 2];
  *(float4*)&wv8[4] = ((const float4*)w)[tid * 2 + 1];
  *(float4*)&bv8[0] = ((const float4*)b)[tid * 2];
  *(float4*)&bv8[4] = ((const float4*)b)[tid * 2 + 1];
  u16 t[8] __attribute__((aligned(16)));
#pragma unroll
  for (int j = 0; j < 8; ++j) t[j] = f2bf((xv[j] - mean) * rs * wv8[j] + bv8[j]);
  *(int4*)&out[(size_t)row * 2048 + tid * 8] = *(int4*)t;
}

// ---------------- RoPE: qr f32 -> qall bf16 (cols 128..191) ----------------
__global__ void k_rope_q(const float* __restrict__ qr, const float* __restrict__ cosT,
                         const float* __restrict__ sinT, u16* __restrict__ qall) {
  int idx = blockIdx.x * 256 + threadIdx.x; // 4096*16*32
  if (idx >= 4096 * 16 * 32) return;
  int i = idx & 31, rest = idx >> 5;
  int h = rest & 15, m = rest >> 4;
  int s = m & 2047, b = m >> 11;
  float c = cosT[s * 32 + i], sn = sinT[s * 32 + i];
  const float* p = qr + (size_t)m * 1024 + h * 64 + i;
  float x0 = p[0], x1 = p[32];
  u16* q = qall + ((size_t)(b * 16 + h) * 2048 + s) * 192 + 128 + i;
  q[0] = f2bf(x0 * c - x1 * sn);
  q[32] = f2bf(x1 * c + x0 * sn);
}

// ---------------- RoPE: kr f32 -> krb_bf bf16 + nkv f32 --------------------
__global__ void k_rope_k(const float* __restrict__ kr, const float* __restrict__ cosT,
                         const float* __restrict__ sinT, float* __restrict__ nkv,
                         u16* __restrict__ krb_bf) {
  int idx = blockIdx.x * 256 + threadIdx.x; // 4096*32
  if (idx >= 4096 * 32) return;
  int i = idx & 31, m = idx >> 5;
  int s = m & 2047;
  float c = cosT[s * 32 + i], sn = sinT[s * 32 + i];
  const float* p = kr + (size_t)m * 64 + i;
  float x0 = p[0], x1 = p[32];
  float y0 = x0 * c - x1 * sn;
  float y1 = x1 * c + x0 * sn;
  nkv[(size_t)m * 576 + 512 + i] = y0;
  nkv[(size_t)m * 576 + 544 + i] = y1;
  krb_bf[(size_t)m * 64 + i] = f2bf(y0);
  krb_bf[(size_t)m * 64 + 32 + i] = f2bf(y1);
}

// ---------------- GEMM: C[M][N] = A[M][K](bf16) * Bt[N][K]^T + bias --------
enum { EP_Q = 0, EP_DKV = 1, EP_KV = 2, EP_RES = 3, EP_GELU = 4 };

template <int EP>
__global__ __launch_bounds__(256) void k_gemm(
    const u16* __restrict__ A, const u16* __restrict__ Bt,
    const float* __restrict__ bias, int K, int Nreal,
    void* out0_, void* out1_, void* out2_, const float* __restrict__ res) {
  __shared__ u16 As[BM * BK];
  __shared__ u16 Bs[BN * BK];
  const int tid = threadIdx.x;
  const int w = tid >> 6, lane = tid & 63;
  const int bm = blockIdx.y * BM, bn = blockIdx.x * BN;
  const int wr = (w >> 1) * 64, wc = (w & 1) * 64;

  const u16* Ag = A + (size_t)(bm + w * 32 + (lane >> 2)) * K + (lane & 3) * 8;
  const u16* Bg = Bt + (size_t)(bn + w * 32 + (lane >> 2)) * K + (lane & 3) * 8;
  char* lA = (char*)As + w * 2048;
  char* lB = (char*)Bs + w * 2048;

  f32x4 acc[4][4] = {};
  for (int k0 = 0; k0 < K; k0 += BK) {
    __syncthreads();
    gload_lds16(Ag, lA);
    gload_lds16(Ag + 16 * K, lA + 1024);
    gload_lds16(Bg, lB);
    gload_lds16(Bg + 16 * K, lB + 1024);
    Ag += BK; Bg += BK;
    __syncthreads();
    const int ka = (lane >> 4) * 8;
    const int lc = lane & 15;
    bf16x8 av[4], bv[4];
#pragma unroll
    for (int i = 0; i < 4; ++i) av[i] = *(const bf16x8*)&As[(wr + i * 16 + lc) * BK + ka];
#pragma unroll
    for (int j = 0; j < 4; ++j) bv[j] = *(const bf16x8*)&Bs[(wc + j * 16 + lc) * BK + ka];
#pragma unroll
    for (int i = 0; i < 4; ++i)
#pragma unroll
      for (int j = 0; j < 4; ++j)
        acc[i][j] = __builtin_amdgcn_mfma_f32_16x16x32_bf16(av[i], bv[j], acc[i][j], 0, 0, 0);
  }

  const int lr = (lane >> 4) * 4, lc = lane & 15;
#pragma unroll
  for (int i = 0; i < 4; ++i) {
#pragma unroll
    for (int j = 0; j < 4; ++j) {
      int col = bn + wc + j * 16 + lc;
      if (col >= Nreal) continue;
      float bb = bias ? bias[col] : 0.f;
#pragma unroll
      for (int r = 0; r < 4; ++r) {
        int row = bm + wr + i * 16 + lr + r;
        int b = row >> 11, s = row & 2047;
        float c = acc[i][j][r] + bb;
        if constexpr (EP == EP_Q) {
          u16* qall = (u16*)out0_; float* qr = (float*)out1_;
          int hh = col / 192, d = col - hh * 192;
          if (d < 128) qall[((size_t)(b * 16 + hh) * 2048 + s) * 192 + d] = f2bf(c);
          else qr[(size_t)row * 1024 + hh * 64 + (d - 128)] = c;
        } else if constexpr (EP == EP_DKV) {
          u16* ckv = (u16*)out0_; float* nkv = (float*)out1_; float* kr = (float*)out2_;
          if (col < 512) { ckv[(size_t)row * 512 + col] = f2bf(c); nkv[(size_t)row * 576 + col] = c; }
          else kr[(size_t)row * 64 + (col - 512)] = c;
        } else if constexpr (EP == EP_KV) {
          u16* knb2h = (u16*)out0_; u16* vv = (u16*)out1_;
          int hh = col >> 8, d = col & 255;
          if (d < 128) knb2h[((size_t)(b * 16 + hh) * 2048 + s) * 128 + d] = f2bf(c);
          else vv[(size_t)row * 2048 + hh * 128 + (d - 128)] = f2bf(c);
        } else if constexpr (EP == EP_RES) {
          float* out = (float*)out0_;
          out[(size_t)row * Nreal + col] = res[(size_t)row * Nreal + col] + c;
        } else { // EP_GELU
          u16* g = (u16*)out0_;
          float gl = 0.5f * c * (1.f + erff(c * 0.70710678118f));
          g[(size_t)row * Nreal + col] = f2bf(gl);
        }
      }
    }
  }
}

// ---------------- Flash attention, register-prefetch pipelined -------------
// grid (32, 32): qt = 31-bx (longest first). Q in regs from qall.
// K tile: kn part [64][128] + kr part [64][64] -> Ks rows 200 u16 (400B).
// V tile from vbT -> Vt rows 72 u16 (144B). Ps rows 72 u16.
// Prefetch tile t+1 into regs during compute of t; raw barriers (no vmcnt drain).
#define QKS 200
#define VPS 72
__global__ __launch_bounds__(256) void k_attn(
    const u16* __restrict__ qall, const u16* __restrict__ knb2h,
    const u16* __restrict__ krb_bf, const u16* __restrict__ vbT,
    u16* __restrict__ o) {
  __shared__ u16 Ks[64 * QKS];
  __shared__ u16 Vt[128 * VPS];
  __shared__ u16 Ps[64 * VPS];
  const int qt = 31 - (int)blockIdx.x;
  const int bh = blockIdx.y, b = bh >> 4;
  const int tid = threadIdx.x, w = tid >> 6, lane = tid & 63;
  const float sc2 = 0.07216878365f * 1.4426950408f; // 1/sqrt(192) * log2(e)
  const int lr = (lane >> 4) * 4, lc = lane & 15, ka = (lane >> 4) * 8;

  // ---- Q fragments in registers ----
  bf16x8 qf[6];
  {
    const u16* qrow = qall + ((size_t)bh * 2048 + qt * 64 + w * 16 + lc) * 192;
#pragma unroll
    for (int ks = 0; ks < 6; ++ks) qf[ks] = *(const bf16x8*)&qrow[ks * 32 + ka];
  }

  const u16* gkn_base = knb2h + (size_t)bh * 2048 * 128;
  const u16* gkr_base = krb_bf + (size_t)b * 2048 * 64;
  const u16* gv_base = vbT + (size_t)bh * 128 * 2048;

  int4 kreg[6], vreg[4];
  auto loadT = [&](int t) {
    const u16* gkn = gkn_base + (size_t)t * 64 * 128;
    const u16* gkr = gkr_base + (size_t)t * 64 * 64;
#pragma unroll
    for (int k = 0; k < 4; ++k) kreg[k] = *(const int4*)(gkn + (tid + k * 256) * 8);
#pragma unroll
    for (int k = 0; k < 2; ++k) kreg[4 + k] = *(const int4*)(gkr + (tid + k * 256) * 8);
#pragma unroll
    for (int k = 0; k < 4; ++k) {
      int li = tid + k * 256, d = li >> 3, rb = li & 7;
      vreg[k] = *(const int4*)(gv_base + (size_t)d * 2048 + t * 64 + rb * 8);
    }
  };
  auto writeT = [&]() {
#pragma unroll
    for (int k = 0; k < 4; ++k) {
      int li = tid + k * 256, r = li >> 4, c = li & 15;
      *(int4*)((char*)Ks + r * 400 + c * 16) = kreg[k];
    }
#pragma unroll
    for (int k = 0; k < 2; ++k) {
      int li = tid + k * 256, r = li >> 3, c = li & 7;
      *(int4*)((char*)Ks + r * 400 + 256 + c * 16) = kreg[4 + k];
    }
#pragma unroll
    for (int k = 0; k < 4; ++k) {
      int li = tid + k * 256, d = li >> 3, rb = li & 7;
      *(int4*)((char*)Vt + d * 144 + rb * 16) = vreg[k];
    }
  };

  float m2[4] = {-1e30f, -1e30f, -1e30f, -1e30f};
  float l2[4] = {0.f, 0.f, 0.f, 0.f};
  f32x4 of[8] = {};

  loadT(0);
  for (int t = 0; t <= qt; ++t) {
    __builtin_amdgcn_s_barrier();       // prev compute done reading LDS
    writeT();
    if (t < qt) loadT(t + 1);           // prefetch stays in flight
    asm volatile("s_waitcnt lgkmcnt(0)" ::: "memory");
    __builtin_amdgcn_s_barrier();       // LDS tile t ready
    __builtin_amdgcn_sched_barrier(0);

    f32x4 sf[4] = {};
    __builtin_amdgcn_s_setprio(1);
#pragma unroll
    for (int j = 0; j < 4; ++j) {
#pragma unroll
      for (int ks = 0; ks < 6; ++ks) {
        bf16x8 kf = *(const bf16x8*)&Ks[(j * 16 + lc) * QKS + ks * 32 + ka];
        sf[j] = __builtin_amdgcn_mfma_f32_16x16x32_bf16(qf[ks], kf, sf[j], 0, 0, 0);
      }
    }
    __builtin_amdgcn_s_setprio(0);

    float rm[4], fpr[4], ps[4];
#pragma unroll
    for (int j = 0; j < 4; ++j)
#pragma unroll
      for (int r = 0; r < 4; ++r) {
        float x_ = sf[j][r] * sc2;
        if (t == qt) {
          int colg = t * 64 + j * 16 + lc;
          int rowg = qt * 64 + w * 16 + lr + r;
          if (colg > rowg) x_ = -1e30f;
        }
        sf[j][r] = x_;
      }
#pragma unroll
    for (int r = 0; r < 4; ++r)
      rm[r] = fmaxf(fmaxf(sf[0][r], sf[1][r]), fmaxf(sf[2][r], sf[3][r]));
#pragma unroll
    for (int msk = 1; msk < 16; msk <<= 1)
#pragma unroll
      for (int r = 0; r < 4; ++r) rm[r] = fmaxf(rm[r], __shfl_xor(rm[r], msk));
#pragma unroll
    for (int r = 0; r < 4; ++r) {
      float mn = fmaxf(m2[r], rm[r]);
      fpr[r] = exp2f(m2[r] - mn);
      m2[r] = mn;
      ps[r] = 0.f;
    }
#pragma unroll
    for (int j = 0; j < 4; ++j)
#pragma unroll
      for (int r = 0; r < 4; ++r) {
        float p = exp2f(sf[j][r] - m2[r]);
        ps[r] += p;
        Ps[(w * 16 + lr + r) * VPS + j * 16 + lc] = f2bf(p);
      }
#pragma unroll
    for (int msk = 1; msk < 16; msk <<= 1)
#pragma unroll
      for (int r = 0; r < 4; ++r) ps[r] += __shfl_xor(ps[r], msk);
#pragma unroll
    for (int r = 0; r < 4; ++r) l2[r] = l2[r] * fpr[r] + ps[r];
#pragma unroll
    for (int nb = 0; nb < 8; ++nb)
#pragma unroll
      for (int r = 0; r < 4; ++r) of[nb][r] *= fpr[r];

    // Ps written/read by same wave only -- lgkm drain suffices.
    asm volatile("s_waitcnt lgkmcnt(0)" ::: "memory");
    __builtin_amdgcn_sched_barrier(0);

    __builtin_amdgcn_s_setprio(1);
#pragma unroll
    for (int ks = 0; ks < 2; ++ks) {
      bf16x8 ap = *(const bf16x8*)&Ps[(w * 16 + lc) * VPS + ks * 32 + ka];
#pragma unroll
      for (int nb = 0; nb < 8; ++nb) {
        bf16x8 bvv = *(const bf16x8*)&Vt[(nb * 16 + lc) * VPS + ks * 32 + ka];
        of[nb] = __builtin_amdgcn_mfma_f32_16x16x32_bf16(ap, bvv, of[nb], 0, 0, 0);
      }
    }
    __builtin_amdgcn_s_setprio(0);
  }

#pragma unroll
  for (int r = 0; r < 4; ++r) {
    float inv = 1.f / l2[r];
    size_t m = (size_t)(bh >> 4) * 2048 + (size_t)qt * 64 + w * 16 + lr + r;
#pragma unroll
    for (int nb = 0; nb < 8; ++nb)
      o[m * 2048 + (bh & 15) * 128 + nb * 16 + lc] = f2bf(of[nb][r] * inv);
  }
}

// ---------------- launch ----------------------------------------------------
extern "C" void kernel_launch(void* const* d_in, const int* in_sizes, int n_in,
                              void* d_out, int out_size, void* d_ws, size_t ws_size,
                              hipStream_t stream) {
  const float* x = (const float*)d_in[0];
  const float* ln1w = (const float*)d_in[1];
  const float* ln1b = (const float*)d_in[2];
  const float* ln2w = (const float*)d_in[3];
  const float* ln2b = (const float*)d_in[4];
  const float* wq = (const float*)d_in[5];
  const float* bq = (const float*)d_in[6];
  const float* wdkv = (const float*)d_in[7];
  const float* bdkv = (const float*)d_in[8];
  const float* wkv = (const float*)d_in[9];
  const float* bkv = (const float*)d_in[10];
  const float* wo = (const float*)d_in[11];
  const float* bo = (const float*)d_in[12];
  const float* w1 = (const float*)d_in[13];
  const float* b1 = (const float*)d_in[14];
  const float* w2 = (const float*)d_in[15];
  const float* b2 = (const float*)d_in[16];
  (void)in_sizes; (void)n_in; (void)out_size; (void)ws_size;

  char* ws = (char*)d_ws;
  size_t off = 0;
  auto alloc = [&](size_t bytes) { void* p = ws + off; off += (bytes + 255) & ~(size_t)255; return p; };

  u16* wqT = (u16*)alloc(3072ull * 2048 * 2);
  u16* wdkvT = (u16*)alloc(640ull * 2048 * 2);   // 576 real rows, padded to 640
  u16* wkvT = (u16*)alloc(4096ull * 512 * 2);
  u16* woT = (u16*)alloc(2048ull * 2048 * 2);
  u16* w1T = (u16*)alloc(8192ull * 2048 * 2);
  u16* w2T = (u16*)alloc(2048ull * 8192 * 2);
  u16* hbuf = (u16*)alloc(4096ull * 2048 * 2);   // LN1 out; reused for LN2 out
  float* cosT = (float*)alloc(2048ull * 32 * 4);
  float* sinT = (float*)alloc(2048ull * 32 * 4);
  u16* obuf = (u16*)alloc(4096ull * 2048 * 2);
  char* G0 = ws + off;                           // FFN g overlays the region below
  u16* qallb = (u16*)alloc(32ull * 2048 * 192 * 2);
  float* qrb = (float*)alloc(4096ull * 1024 * 4);
  u16* ckvb = (u16*)alloc(4096ull * 512 * 2);
  float* krb = (float*)alloc(4096ull * 64 * 4);
  u16* krb_bf = (u16*)alloc(4096ull * 64 * 2);
  u16* knb2h = (u16*)alloc(32ull * 2048 * 128 * 2);
  u16* vb = (u16*)alloc(4096ull * 2048 * 2);
  u16* vbT = (u16*)alloc(32ull * 128 * 2048 * 2);
  u16* gb = (u16*)G0;                            // 67.1MB <= region below (~98MB)

  float* xout = (float*)d_out;                   // [4096][2048]
  float* nkv = xout + 4096ull * 2048;            // [4096][576]

  dim3 blk(256);
  k_transpose_bf16<<<dim3(64, 96), blk, 0, stream>>>(wq, wqT, 2048, 3072);
  k_transpose_bf16<<<dim3(64, 18), blk, 0, stream>>>(wdkv, wdkvT, 2048, 576);
  k_transpose_bf16<<<dim3(16, 128), blk, 0, stream>>>(wkv, wkvT, 512, 4096);
  k_transpose_bf16<<<dim3(64, 64), blk, 0, stream>>>(wo, woT, 2048, 2048);
  k_transpose_bf16<<<dim3(64, 256), blk, 0, stream>>>(w1, w1T, 2048, 8192);
  k_transpose_bf16<<<dim3(256, 64), blk, 0, stream>>>(w2, w2T, 8192, 2048);
  k_rope_table<<<dim3(256), blk, 0, stream>>>(cosT, sinT);
  k_ln<<<dim3(4096), blk, 0, stream>>>(x, ln1w, ln1b, hbuf);
  k_gemm<EP_Q><<<dim3(24, 32), blk, 0, stream>>>(hbuf, wqT, bq, 2048, 3072, qallb, qrb, nullptr, nullptr);
  k_gemm<EP_DKV><<<dim3(5, 32), blk, 0, stream>>>(hbuf, wdkvT, bdkv, 2048, 576, ckvb, nkv, krb, nullptr);
  k_rope_q<<<dim3(8192), blk, 0, stream>>>(qrb, cosT, sinT, qallb);
  k_rope_k<<<dim3(512), blk, 0, stream>>>(krb, cosT, sinT, nkv, krb_bf);
  k_gemm<EP_KV><<<dim3(32, 32), blk, 0, stream>>>(ckvb, wkvT, bkv, 512, 4096, knb2h, vb, nullptr, nullptr);
  k_transpose_v<<<dim3(64, 4, 32), blk, 0, stream>>>(vb, vbT);
  k_attn<<<dim3(32, 32), blk, 0, stream>>>(qallb, knb2h, krb_bf, vbT, obuf);
  k_gemm<EP_RES><<<dim3(16, 32), blk, 0, stream>>>(obuf, woT, bo, 2048, 2048, xout, nullptr, nullptr, x);
  k_ln<<<dim3(4096), blk, 0, stream>>>(xout, ln2w, ln2b, hbuf);
  k_gemm<EP_GELU><<<dim3(64, 32), blk, 0, stream>>>(hbuf, w1T, b1, 2048, 8192, gb, nullptr, nullptr, nullptr);
  k_gemm<EP_RES><<<dim3(16, 32), blk, 0, stream>>>(gb, w2T, b2, 8192, 2048, xout, nullptr, nullptr, xout);
}

// Round 5
// 1064.154 us; speedup vs baseline: 1.3453x; 1.1343x over previous
//
#include <hip/hip_runtime.h>
#include <hip/hip_bf16.h>

// MLA transformer block on MI355X. Round 5: fix attn register-spill
// (__launch_bounds__(256,2) -> no scratch round-trip for prefetch regs),
// XCD-locality block remap so each (b,h)'s K/V stays in one XCD's L2.

typedef short bf16x8 __attribute__((ext_vector_type(8)));
typedef float f32x4 __attribute__((ext_vector_type(4)));
typedef unsigned short u16;

#define BM 128
#define BN 128
#define BK 32

__device__ __forceinline__ u16 f2bf(float f) {
  unsigned int u = __builtin_bit_cast(unsigned int, f);
  u += 0x7FFFu + ((u >> 16) & 1u);
  return (u16)(u >> 16);
}

__device__ __forceinline__ void gload_lds16(const void* g, void* l) {
  __builtin_amdgcn_global_load_lds(
      (const __attribute__((address_space(1))) unsigned int*)(uintptr_t)g,
      (__attribute__((address_space(3))) unsigned int*)(unsigned int)(uintptr_t)l,
      16, 0, 0);
}

// ---------------- transpose + f32->bf16 : out[N][K] = (bf16) in[K][N] ------
__global__ __launch_bounds__(256) void k_transpose_bf16(
    const float* __restrict__ in, u16* __restrict__ out, int K, int N) {
  __shared__ float tile[32][33];
  int k0 = blockIdx.x * 32, n0 = blockIdx.y * 32;
  int tx = threadIdx.x & 31, ty = threadIdx.x >> 5;
#pragma unroll
  for (int i = 0; i < 4; ++i) {
    int k = k0 + ty + i * 8, n = n0 + tx;
    tile[ty + i * 8][tx] = (k < K && n < N) ? in[(size_t)k * N + n] : 0.f;
  }
  __syncthreads();
#pragma unroll
  for (int i = 0; i < 4; ++i) {
    int n = n0 + ty + i * 8, k = k0 + tx;
    if (n < N && k < K) out[(size_t)n * K + k] = f2bf(tile[tx][ty + i * 8]);
  }
}

// ---------------- V transpose per (b,h): vb[m][h*128+d] -> vbT[bh][d][s] ----
__global__ __launch_bounds__(256) void k_transpose_v(
    const u16* __restrict__ vb, u16* __restrict__ vbT) {
  __shared__ u16 tile[32][34];
  int bh = blockIdx.z, b = bh >> 4, h = bh & 15;
  int s0 = blockIdx.x * 32, d0 = blockIdx.y * 32;
  int tx = threadIdx.x & 31, ty = threadIdx.x >> 5;
#pragma unroll
  for (int i = 0; i < 4; ++i)
    tile[ty + i * 8][tx] =
        vb[((size_t)b * 2048 + s0 + ty + i * 8) * 2048 + h * 128 + d0 + tx];
  __syncthreads();
#pragma unroll
  for (int i = 0; i < 4; ++i)
    vbT[((size_t)bh * 128 + d0 + ty + i * 8) * 2048 + s0 + tx] = tile[tx][ty + i * 8];
}

// ---------------- RoPE tables: cos/sin[s][i], i<32 -------------------------
__global__ void k_rope_table(float* __restrict__ cosT, float* __restrict__ sinT) {
  int idx = blockIdx.x * 256 + threadIdx.x;
  if (idx >= 2048 * 32) return;
  int s = idx >> 5, i = idx & 31;
  float inv = exp2f(-(float)i * 0.41524101186092037f); // log2(10000)/32
  float a = (float)s * inv;
  cosT[idx] = cosf(a);
  sinT[idx] = sinf(a);
}

// ---------------- LayerNorm row=2048, out bf16 -----------------------------
__global__ __launch_bounds__(256) void k_ln(const float* __restrict__ x,
                                            const float* __restrict__ w,
                                            const float* __restrict__ b,
                                            u16* __restrict__ out) {
  const int row = blockIdx.x, tid = threadIdx.x;
  const float* xr = x + (size_t)row * 2048;
  float xv[8];
  *(float4*)&xv[0] = ((const float4*)xr)[tid * 2];
  *(float4*)&xv[4] = ((const float4*)xr)[tid * 2 + 1];
  float s = 0.f, ss = 0.f;
#pragma unroll
  for (int j = 0; j < 8; ++j) { s += xv[j]; ss += xv[j] * xv[j]; }
#pragma unroll
  for (int m_ = 32; m_; m_ >>= 1) { s += __shfl_xor(s, m_); ss += __shfl_xor(ss, m_); }
  __shared__ float red[8];
  const int wv = tid >> 6;
  if ((tid & 63) == 0) { red[wv] = s; red[wv + 4] = ss; }
  __syncthreads();
  s = red[0] + red[1] + red[2] + red[3];
  ss = red[4] + red[5] + red[6] + red[7];
  const float mean = s * (1.f / 2048.f);
  const float rs = rsqrtf(ss * (1.f / 2048.f) - mean * mean + 1e-5f);
  float wv8[8], bv8[8];
  *(float4*)&wv8[0] = ((const float4*)w)[tid * 2];
  *(float4*)&wv8[4] = ((const float4*)w)[tid * 2 + 1];
  *(float4*)&bv8[0] = ((const float4*)b)[tid * 2];
  *(float4*)&bv8[4] = ((const float4*)b)[tid * 2 + 1];
  u16 t[8] __attribute__((aligned(16)));
#pragma unroll
  for (int j = 0; j < 8; ++j) t[j] = f2bf((xv[j] - mean) * rs * wv8[j] + bv8[j]);
  *(int4*)&out[(size_t)row * 2048 + tid * 8] = *(int4*)t;
}

// ---------------- RoPE: qr f32 -> qall bf16 (cols 128..191) ----------------
__global__ void k_rope_q(const float* __restrict__ qr, const float* __restrict__ cosT,
                         const float* __restrict__ sinT, u16* __restrict__ qall) {
  int idx = blockIdx.x * 256 + threadIdx.x; // 4096*16*32
  if (idx >= 4096 * 16 * 32) return;
  int i = idx & 31, rest = idx >> 5;
  int h = rest & 15, m = rest >> 4;
  int s = m & 2047, b = m >> 11;
  float c = cosT[s * 32 + i], sn = sinT[s * 32 + i];
  const float* p = qr + (size_t)m * 1024 + h * 64 + i;
  float x0 = p[0], x1 = p[32];
  u16* q = qall + ((size_t)(b * 16 + h) * 2048 + s) * 192 + 128 + i;
  q[0] = f2bf(x0 * c - x1 * sn);
  q[32] = f2bf(x1 * c + x0 * sn);
}

// ---------------- RoPE: kr f32 -> krb_bf bf16 + nkv f32 --------------------
__global__ void k_rope_k(const float* __restrict__ kr, const float* __restrict__ cosT,
                         const float* __restrict__ sinT, float* __restrict__ nkv,
                         u16* __restrict__ krb_bf) {
  int idx = blockIdx.x * 256 + threadIdx.x; // 4096*32
  if (idx >= 4096 * 32) return;
  int i = idx & 31, m = idx >> 5;
  int s = m & 2047;
  float c = cosT[s * 32 + i], sn = sinT[s * 32 + i];
  const float* p = kr + (size_t)m * 64 + i;
  float x0 = p[0], x1 = p[32];
  float y0 = x0 * c - x1 * sn;
  float y1 = x1 * c + x0 * sn;
  nkv[(size_t)m * 576 + 512 + i] = y0;
  nkv[(size_t)m * 576 + 544 + i] = y1;
  krb_bf[(size_t)m * 64 + i] = f2bf(y0);
  krb_bf[(size_t)m * 64 + 32 + i] = f2bf(y1);
}

// ---------------- GEMM: C[M][N] = A[M][K](bf16) * Bt[N][K]^T + bias --------
enum { EP_Q = 0, EP_DKV = 1, EP_KV = 2, EP_RES = 3, EP_GELU = 4 };

template <int EP>
__global__ __launch_bounds__(256) void k_gemm(
    const u16* __restrict__ A, const u16* __restrict__ Bt,
    const float* __restrict__ bias, int K, int Nreal,
    void* out0_, void* out1_, void* out2_, const float* __restrict__ res) {
  __shared__ u16 As[BM * BK];
  __shared__ u16 Bs[BN * BK];
  const int tid = threadIdx.x;
  const int w = tid >> 6, lane = tid & 63;
  const int bm = blockIdx.y * BM, bn = blockIdx.x * BN;
  const int wr = (w >> 1) * 64, wc = (w & 1) * 64;

  const u16* Ag = A + (size_t)(bm + w * 32 + (lane >> 2)) * K + (lane & 3) * 8;
  const u16* Bg = Bt + (size_t)(bn + w * 32 + (lane >> 2)) * K + (lane & 3) * 8;
  char* lA = (char*)As + w * 2048;
  char* lB = (char*)Bs + w * 2048;

  f32x4 acc[4][4] = {};
  for (int k0 = 0; k0 < K; k0 += BK) {
    __syncthreads();
    gload_lds16(Ag, lA);
    gload_lds16(Ag + 16 * K, lA + 1024);
    gload_lds16(Bg, lB);
    gload_lds16(Bg + 16 * K, lB + 1024);
    Ag += BK; Bg += BK;
    __syncthreads();
    const int ka = (lane >> 4) * 8;
    const int lc = lane & 15;
    bf16x8 av[4], bv[4];
#pragma unroll
    for (int i = 0; i < 4; ++i) av[i] = *(const bf16x8*)&As[(wr + i * 16 + lc) * BK + ka];
#pragma unroll
    for (int j = 0; j < 4; ++j) bv[j] = *(const bf16x8*)&Bs[(wc + j * 16 + lc) * BK + ka];
#pragma unroll
    for (int i = 0; i < 4; ++i)
#pragma unroll
      for (int j = 0; j < 4; ++j)
        acc[i][j] = __builtin_amdgcn_mfma_f32_16x16x32_bf16(av[i], bv[j], acc[i][j], 0, 0, 0);
  }

  const int lr = (lane >> 4) * 4, lc = lane & 15;
#pragma unroll
  for (int i = 0; i < 4; ++i) {
#pragma unroll
    for (int j = 0; j < 4; ++j) {
      int col = bn + wc + j * 16 + lc;
      if (col >= Nreal) continue;
      float bb = bias ? bias[col] : 0.f;
#pragma unroll
      for (int r = 0; r < 4; ++r) {
        int row = bm + wr + i * 16 + lr + r;
        int b = row >> 11, s = row & 2047;
        float c = acc[i][j][r] + bb;
        if constexpr (EP == EP_Q) {
          u16* qall = (u16*)out0_; float* qr = (float*)out1_;
          int hh = col / 192, d = col - hh * 192;
          if (d < 128) qall[((size_t)(b * 16 + hh) * 2048 + s) * 192 + d] = f2bf(c);
          else qr[(size_t)row * 1024 + hh * 64 + (d - 128)] = c;
        } else if constexpr (EP == EP_DKV) {
          u16* ckv = (u16*)out0_; float* nkv = (float*)out1_; float* kr = (float*)out2_;
          if (col < 512) { ckv[(size_t)row * 512 + col] = f2bf(c); nkv[(size_t)row * 576 + col] = c; }
          else kr[(size_t)row * 64 + (col - 512)] = c;
        } else if constexpr (EP == EP_KV) {
          u16* knb2h = (u16*)out0_; u16* vv = (u16*)out1_;
          int hh = col >> 8, d = col & 255;
          if (d < 128) knb2h[((size_t)(b * 16 + hh) * 2048 + s) * 128 + d] = f2bf(c);
          else vv[(size_t)row * 2048 + hh * 128 + (d - 128)] = f2bf(c);
        } else if constexpr (EP == EP_RES) {
          float* out = (float*)out0_;
          out[(size_t)row * Nreal + col] = res[(size_t)row * Nreal + col] + c;
        } else { // EP_GELU
          u16* g = (u16*)out0_;
          float gl = 0.5f * c * (1.f + erff(c * 0.70710678118f));
          g[(size_t)row * Nreal + col] = f2bf(gl);
        }
      }
    }
  }
}

// ---------------- Flash attention, register-prefetch pipelined -------------
// 1D grid 1024. lin = ((qt'*4 + bh_hi)<<3) | bh_lo so all q-tiles of one
// (b,h) share lin&7 -> same XCD under round-robin dispatch; qt'=0 is the
// longest tile (qt = 31 - qt'). launch_bounds(256,2): VGPR cap 256, no spill.
#define QKS 200
#define VPS 72
__global__ __launch_bounds__(256, 2) void k_attn(
    const u16* __restrict__ qall, const u16* __restrict__ knb2h,
    const u16* __restrict__ krb_bf, const u16* __restrict__ vbT,
    u16* __restrict__ o) {
  __shared__ u16 Ks[64 * QKS];
  __shared__ u16 Vt[128 * VPS];
  __shared__ u16 Ps[64 * VPS];
  const int lin = blockIdx.x;
  const int qt = 31 - (lin >> 5);
  const int bh = (((lin >> 3) & 3) << 3) | (lin & 7);
  const int b = bh >> 4;
  const int tid = threadIdx.x, w = tid >> 6, lane = tid & 63;
  const float sc2 = 0.07216878365f * 1.4426950408f; // 1/sqrt(192) * log2(e)
  const int lr = (lane >> 4) * 4, lc = lane & 15, ka = (lane >> 4) * 8;

  // ---- Q fragments in registers ----
  bf16x8 qf[6];
  {
    const u16* qrow = qall + ((size_t)bh * 2048 + qt * 64 + w * 16 + lc) * 192;
#pragma unroll
    for (int ks = 0; ks < 6; ++ks) qf[ks] = *(const bf16x8*)&qrow[ks * 32 + ka];
  }

  const u16* gkn_base = knb2h + (size_t)bh * 2048 * 128;
  const u16* gkr_base = krb_bf + (size_t)b * 2048 * 64;
  const u16* gv_base = vbT + (size_t)bh * 128 * 2048;

  int4 kreg[6], vreg[4];
  auto loadT = [&](int t) {
    const u16* gkn = gkn_base + (size_t)t * 64 * 128;
    const u16* gkr = gkr_base + (size_t)t * 64 * 64;
#pragma unroll
    for (int k = 0; k < 4; ++k) kreg[k] = *(const int4*)(gkn + (tid + k * 256) * 8);
#pragma unroll
    for (int k = 0; k < 2; ++k) kreg[4 + k] = *(const int4*)(gkr + (tid + k * 256) * 8);
#pragma unroll
    for (int k = 0; k < 4; ++k) {
      int li = tid + k * 256, d = li >> 3, rb = li & 7;
      vreg[k] = *(const int4*)(gv_base + (size_t)d * 2048 + t * 64 + rb * 8);
    }
  };
  auto writeT = [&]() {
#pragma unroll
    for (int k = 0; k < 4; ++k) {
      int li = tid + k * 256, r = li >> 4, c = li & 15;
      *(int4*)((char*)Ks + r * 400 + c * 16) = kreg[k];
    }
#pragma unroll
    for (int k = 0; k < 2; ++k) {
      int li = tid + k * 256, r = li >> 3, c = li & 7;
      *(int4*)((char*)Ks + r * 400 + 256 + c * 16) = kreg[4 + k];
    }
#pragma unroll
    for (int k = 0; k < 4; ++k) {
      int li = tid + k * 256, d = li >> 3, rb = li & 7;
      *(int4*)((char*)Vt + d * 144 + rb * 16) = vreg[k];
    }
  };

  float m2[4] = {-1e30f, -1e30f, -1e30f, -1e30f};
  float l2[4] = {0.f, 0.f, 0.f, 0.f};
  f32x4 of[8] = {};

  loadT(0);
  for (int t = 0; t <= qt; ++t) {
    __builtin_amdgcn_s_barrier();       // prev compute done reading LDS
    writeT();
    if (t < qt) loadT(t + 1);           // prefetch stays in flight
    asm volatile("s_waitcnt lgkmcnt(0)" ::: "memory");
    __builtin_amdgcn_s_barrier();       // LDS tile t ready
    __builtin_amdgcn_sched_barrier(0);

    f32x4 sf[4] = {};
    __builtin_amdgcn_s_setprio(1);
#pragma unroll
    for (int j = 0; j < 4; ++j) {
#pragma unroll
      for (int ks = 0; ks < 6; ++ks) {
        bf16x8 kf = *(const bf16x8*)&Ks[(j * 16 + lc) * QKS + ks * 32 + ka];
        sf[j] = __builtin_amdgcn_mfma_f32_16x16x32_bf16(qf[ks], kf, sf[j], 0, 0, 0);
      }
    }
    __builtin_amdgcn_s_setprio(0);

    float rm[4], fpr[4], ps[4];
#pragma unroll
    for (int j = 0; j < 4; ++j)
#pragma unroll
      for (int r = 0; r < 4; ++r) {
        float x_ = sf[j][r] * sc2;
        if (t == qt) {
          int colg = t * 64 + j * 16 + lc;
          int rowg = qt * 64 + w * 16 + lr + r;
          if (colg > rowg) x_ = -1e30f;
        }
        sf[j][r] = x_;
      }
#pragma unroll
    for (int r = 0; r < 4; ++r)
      rm[r] = fmaxf(fmaxf(sf[0][r], sf[1][r]), fmaxf(sf[2][r], sf[3][r]));
#pragma unroll
    for (int msk = 1; msk < 16; msk <<= 1)
#pragma unroll
      for (int r = 0; r < 4; ++r) rm[r] = fmaxf(rm[r], __shfl_xor(rm[r], msk));
#pragma unroll
    for (int r = 0; r < 4; ++r) {
      float mn = fmaxf(m2[r], rm[r]);
      fpr[r] = exp2f(m2[r] - mn);
      m2[r] = mn;
      ps[r] = 0.f;
    }
#pragma unroll
    for (int j = 0; j < 4; ++j)
#pragma unroll
      for (int r = 0; r < 4; ++r) {
        float p = exp2f(sf[j][r] - m2[r]);
        ps[r] += p;
        Ps[(w * 16 + lr + r) * VPS + j * 16 + lc] = f2bf(p);
      }
#pragma unroll
    for (int msk = 1; msk < 16; msk <<= 1)
#pragma unroll
      for (int r = 0; r < 4; ++r) ps[r] += __shfl_xor(ps[r], msk);
#pragma unroll
    for (int r = 0; r < 4; ++r) l2[r] = l2[r] * fpr[r] + ps[r];
#pragma unroll
    for (int nb = 0; nb < 8; ++nb)
#pragma unroll
      for (int r = 0; r < 4; ++r) of[nb][r] *= fpr[r];

    // Ps written/read by same wave only -- lgkm drain suffices.
    asm volatile("s_waitcnt lgkmcnt(0)" ::: "memory");
    __builtin_amdgcn_sched_barrier(0);

    __builtin_amdgcn_s_setprio(1);
#pragma unroll
    for (int ks = 0; ks < 2; ++ks) {
      bf16x8 ap = *(const bf16x8*)&Ps[(w * 16 + lc) * VPS + ks * 32 + ka];
#pragma unroll
      for (int nb = 0; nb < 8; ++nb) {
        bf16x8 bvv = *(const bf16x8*)&Vt[(nb * 16 + lc) * VPS + ks * 32 + ka];
        of[nb] = __builtin_amdgcn_mfma_f32_16x16x32_bf16(ap, bvv, of[nb], 0, 0, 0);
      }
    }
    __builtin_amdgcn_s_setprio(0);
  }

#pragma unroll
  for (int r = 0; r < 4; ++r) {
    float inv = 1.f / l2[r];
    size_t m = (size_t)(bh >> 4) * 2048 + (size_t)qt * 64 + w * 16 + lr + r;
#pragma unroll
    for (int nb = 0; nb < 8; ++nb)
      o[m * 2048 + (bh & 15) * 128 + nb * 16 + lc] = f2bf(of[nb][r] * inv);
  }
}

// ---------------- launch ----------------------------------------------------
extern "C" void kernel_launch(void* const* d_in, const int* in_sizes, int n_in,
                              void* d_out, int out_size, void* d_ws, size_t ws_size,
                              hipStream_t stream) {
  const float* x = (const float*)d_in[0];
  const float* ln1w = (const float*)d_in[1];
  const float* ln1b = (const float*)d_in[2];
  const float* ln2w = (const float*)d_in[3];
  const float* ln2b = (const float*)d_in[4];
  const float* wq = (const float*)d_in[5];
  const float* bq = (const float*)d_in[6];
  const float* wdkv = (const float*)d_in[7];
  const float* bdkv = (const float*)d_in[8];
  const float* wkv = (const float*)d_in[9];
  const float* bkv = (const float*)d_in[10];
  const float* wo = (const float*)d_in[11];
  const float* bo = (const float*)d_in[12];
  const float* w1 = (const float*)d_in[13];
  const float* b1 = (const float*)d_in[14];
  const float* w2 = (const float*)d_in[15];
  const float* b2 = (const float*)d_in[16];
  (void)in_sizes; (void)n_in; (void)out_size; (void)ws_size;

  char* ws = (char*)d_ws;
  size_t off = 0;
  auto alloc = [&](size_t bytes) { void* p = ws + off; off += (bytes + 255) & ~(size_t)255; return p; };

  u16* wqT = (u16*)alloc(3072ull * 2048 * 2);
  u16* wdkvT = (u16*)alloc(640ull * 2048 * 2);   // 576 real rows, padded to 640
  u16* wkvT = (u16*)alloc(4096ull * 512 * 2);
  u16* woT = (u16*)alloc(2048ull * 2048 * 2);
  u16* w1T = (u16*)alloc(8192ull * 2048 * 2);
  u16* w2T = (u16*)alloc(2048ull * 8192 * 2);
  u16* hbuf = (u16*)alloc(4096ull * 2048 * 2);   // LN1 out; reused for LN2 out
  float* cosT = (float*)alloc(2048ull * 32 * 4);
  float* sinT = (float*)alloc(2048ull * 32 * 4);
  u16* obuf = (u16*)alloc(4096ull * 2048 * 2);
  char* G0 = ws + off;                           // FFN g overlays the region below
  u16* qallb = (u16*)alloc(32ull * 2048 * 192 * 2);
  float* qrb = (float*)alloc(4096ull * 1024 * 4);
  u16* ckvb = (u16*)alloc(4096ull * 512 * 2);
  float* krb = (float*)alloc(4096ull * 64 * 4);
  u16* krb_bf = (u16*)alloc(4096ull * 64 * 2);
  u16* knb2h = (u16*)alloc(32ull * 2048 * 128 * 2);
  u16* vb = (u16*)alloc(4096ull * 2048 * 2);
  u16* vbT = (u16*)alloc(32ull * 128 * 2048 * 2);
  u16* gb = (u16*)G0;                            // 67.1MB <= region below (~98MB)

  float* xout = (float*)d_out;                   // [4096][2048]
  float* nkv = xout + 4096ull * 2048;            // [4096][576]

  dim3 blk(256);
  k_transpose_bf16<<<dim3(64, 96), blk, 0, stream>>>(wq, wqT, 2048, 3072);
  k_transpose_bf16<<<dim3(64, 18), blk, 0, stream>>>(wdkv, wdkvT, 2048, 576);
  k_transpose_bf16<<<dim3(16, 128), blk, 0, stream>>>(wkv, wkvT, 512, 4096);
  k_transpose_bf16<<<dim3(64, 64), blk, 0, stream>>>(wo, woT, 2048, 2048);
  k_transpose_bf16<<<dim3(64, 256), blk, 0, stream>>>(w1, w1T, 2048, 8192);
  k_transpose_bf16<<<dim3(256, 64), blk, 0, stream>>>(w2, w2T, 8192, 2048);
  k_rope_table<<<dim3(256), blk, 0, stream>>>(cosT, sinT);
  k_ln<<<dim3(4096), blk, 0, stream>>>(x, ln1w, ln1b, hbuf);
  k_gemm<EP_Q><<<dim3(24, 32), blk, 0, stream>>>(hbuf, wqT, bq, 2048, 3072, qallb, qrb, nullptr, nullptr);
  k_gemm<EP_DKV><<<dim3(5, 32), blk, 0, stream>>>(hbuf, wdkvT, bdkv, 2048, 576, ckvb, nkv, krb, nullptr);
  k_rope_q<<<dim3(8192), blk, 0, stream>>>(qrb, cosT, sinT, qallb);
  k_rope_k<<<dim3(512), blk, 0, stream>>>(krb, cosT, sinT, nkv, krb_bf);
  k_gemm<EP_KV><<<dim3(32, 32), blk, 0, stream>>>(ckvb, wkvT, bkv, 512, 4096, knb2h, vb, nullptr, nullptr);
  k_transpose_v<<<dim3(64, 4, 32), blk, 0, stream>>>(vb, vbT);
  k_attn<<<dim3(1024), blk, 0, stream>>>(qallb, knb2h, krb_bf, vbT, obuf);
  k_gemm<EP_RES><<<dim3(16, 32), blk, 0, stream>>>(obuf, woT, bo, 2048, 2048, xout, nullptr, nullptr, x);
  k_ln<<<dim3(4096), blk, 0, stream>>>(xout, ln2w, ln2b, hbuf);
  k_gemm<EP_GELU><<<dim3(64, 32), blk, 0, stream>>>(hbuf, w1T, b1, 2048, 8192, gb, nullptr, nullptr, nullptr);
  k_gemm<EP_RES><<<dim3(16, 32), blk, 0, stream>>>(gb, w2T, b2, 8192, 2048, xout, nullptr, nullptr, xout);
}

// Round 6
// 1015.918 us; speedup vs baseline: 1.4092x; 1.0475x over previous
//
#include <hip/hip_runtime.h>
#include <hip/hip_bf16.h>

// MLA transformer block on MI355X. Round 6: big GEMMs moved to
// 128x256xBK64 8-wave double-buffered single-barrier structure (T3 minimum
// 2-phase recipe) + XCD-chunked block swizzle for L2 panel reuse.

typedef short bf16x8 __attribute__((ext_vector_type(8)));
typedef float f32x4 __attribute__((ext_vector_type(4)));
typedef unsigned short u16;

#define BM 128
#define BN 128
#define BK 32

__device__ __forceinline__ u16 f2bf(float f) {
  unsigned int u = __builtin_bit_cast(unsigned int, f);
  u += 0x7FFFu + ((u >> 16) & 1u);
  return (u16)(u >> 16);
}

__device__ __forceinline__ void gload_lds16(const void* g, void* l) {
  __builtin_amdgcn_global_load_lds(
      (const __attribute__((address_space(1))) unsigned int*)(uintptr_t)g,
      (__attribute__((address_space(3))) unsigned int*)(unsigned int)(uintptr_t)l,
      16, 0, 0);
}

// ---------------- transpose + f32->bf16 : out[N][K] = (bf16) in[K][N] ------
__global__ __launch_bounds__(256) void k_transpose_bf16(
    const float* __restrict__ in, u16* __restrict__ out, int K, int N) {
  __shared__ float tile[32][33];
  int k0 = blockIdx.x * 32, n0 = blockIdx.y * 32;
  int tx = threadIdx.x & 31, ty = threadIdx.x >> 5;
#pragma unroll
  for (int i = 0; i < 4; ++i) {
    int k = k0 + ty + i * 8, n = n0 + tx;
    tile[ty + i * 8][tx] = (k < K && n < N) ? in[(size_t)k * N + n] : 0.f;
  }
  __syncthreads();
#pragma unroll
  for (int i = 0; i < 4; ++i) {
    int n = n0 + ty + i * 8, k = k0 + tx;
    if (n < N && k < K) out[(size_t)n * K + k] = f2bf(tile[tx][ty + i * 8]);
  }
}

// ---------------- V transpose per (b,h): vb[m][h*128+d] -> vbT[bh][d][s] ----
__global__ __launch_bounds__(256) void k_transpose_v(
    const u16* __restrict__ vb, u16* __restrict__ vbT) {
  __shared__ u16 tile[32][34];
  int bh = blockIdx.z, b = bh >> 4, h = bh & 15;
  int s0 = blockIdx.x * 32, d0 = blockIdx.y * 32;
  int tx = threadIdx.x & 31, ty = threadIdx.x >> 5;
#pragma unroll
  for (int i = 0; i < 4; ++i)
    tile[ty + i * 8][tx] =
        vb[((size_t)b * 2048 + s0 + ty + i * 8) * 2048 + h * 128 + d0 + tx];
  __syncthreads();
#pragma unroll
  for (int i = 0; i < 4; ++i)
    vbT[((size_t)bh * 128 + d0 + ty + i * 8) * 2048 + s0 + tx] = tile[tx][ty + i * 8];
}

// ---------------- RoPE tables: cos/sin[s][i], i<32 -------------------------
__global__ void k_rope_table(float* __restrict__ cosT, float* __restrict__ sinT) {
  int idx = blockIdx.x * 256 + threadIdx.x;
  if (idx >= 2048 * 32) return;
  int s = idx >> 5, i = idx & 31;
  float inv = exp2f(-(float)i * 0.41524101186092037f); // log2(10000)/32
  float a = (float)s * inv;
  cosT[idx] = cosf(a);
  sinT[idx] = sinf(a);
}

// ---------------- LayerNorm row=2048, out bf16 -----------------------------
__global__ __launch_bounds__(256) void k_ln(const float* __restrict__ x,
                                            const float* __restrict__ w,
                                            const float* __restrict__ b,
                                            u16* __restrict__ out) {
  const int row = blockIdx.x, tid = threadIdx.x;
  const float* xr = x + (size_t)row * 2048;
  float xv[8];
  *(float4*)&xv[0] = ((const float4*)xr)[tid * 2];
  *(float4*)&xv[4] = ((const float4*)xr)[tid * 2 + 1];
  float s = 0.f, ss = 0.f;
#pragma unroll
  for (int j = 0; j < 8; ++j) { s += xv[j]; ss += xv[j] * xv[j]; }
#pragma unroll
  for (int m_ = 32; m_; m_ >>= 1) { s += __shfl_xor(s, m_); ss += __shfl_xor(ss, m_); }
  __shared__ float red[8];
  const int wv = tid >> 6;
  if ((tid & 63) == 0) { red[wv] = s; red[wv + 4] = ss; }
  __syncthreads();
  s = red[0] + red[1] + red[2] + red[3];
  ss = red[4] + red[5] + red[6] + red[7];
  const float mean = s * (1.f / 2048.f);
  const float rs = rsqrtf(ss * (1.f / 2048.f) - mean * mean + 1e-5f);
  float wv8[8], bv8[8];
  *(float4*)&wv8[0] = ((const float4*)w)[tid * 2];
  *(float4*)&wv8[4] = ((const float4*)w)[tid * 2 + 1];
  *(float4*)&bv8[0] = ((const float4*)b)[tid * 2];
  *(float4*)&bv8[4] = ((const float4*)b)[tid * 2 + 1];
  u16 t[8] __attribute__((aligned(16)));
#pragma unroll
  for (int j = 0; j < 8; ++j) t[j] = f2bf((xv[j] - mean) * rs * wv8[j] + bv8[j]);
  *(int4*)&out[(size_t)row * 2048 + tid * 8] = *(int4*)t;
}

// ---------------- RoPE: qr f32 -> qall bf16 (cols 128..191) ----------------
__global__ void k_rope_q(const float* __restrict__ qr, const float* __restrict__ cosT,
                         const float* __restrict__ sinT, u16* __restrict__ qall) {
  int idx = blockIdx.x * 256 + threadIdx.x; // 4096*16*32
  if (idx >= 4096 * 16 * 32) return;
  int i = idx & 31, rest = idx >> 5;
  int h = rest & 15, m = rest >> 4;
  int s = m & 2047, b = m >> 11;
  float c = cosT[s * 32 + i], sn = sinT[s * 32 + i];
  const float* p = qr + (size_t)m * 1024 + h * 64 + i;
  float x0 = p[0], x1 = p[32];
  u16* q = qall + ((size_t)(b * 16 + h) * 2048 + s) * 192 + 128 + i;
  q[0] = f2bf(x0 * c - x1 * sn);
  q[32] = f2bf(x1 * c + x0 * sn);
}

// ---------------- RoPE: kr f32 -> krb_bf bf16 + nkv f32 --------------------
__global__ void k_rope_k(const float* __restrict__ kr, const float* __restrict__ cosT,
                         const float* __restrict__ sinT, float* __restrict__ nkv,
                         u16* __restrict__ krb_bf) {
  int idx = blockIdx.x * 256 + threadIdx.x; // 4096*32
  if (idx >= 4096 * 32) return;
  int i = idx & 31, m = idx >> 5;
  int s = m & 2047;
  float c = cosT[s * 32 + i], sn = sinT[s * 32 + i];
  const float* p = kr + (size_t)m * 64 + i;
  float x0 = p[0], x1 = p[32];
  float y0 = x0 * c - x1 * sn;
  float y1 = x1 * c + x0 * sn;
  nkv[(size_t)m * 576 + 512 + i] = y0;
  nkv[(size_t)m * 576 + 544 + i] = y1;
  krb_bf[(size_t)m * 64 + i] = f2bf(y0);
  krb_bf[(size_t)m * 64 + 32 + i] = f2bf(y1);
}

enum { EP_Q = 0, EP_DKV = 1, EP_KV = 2, EP_RES = 3, EP_GELU = 4 };

// ---------------- small GEMM (dkv only): m97 128x128xBK32 ------------------
template <int EP>
__global__ __launch_bounds__(256) void k_gemm(
    const u16* __restrict__ A, const u16* __restrict__ Bt,
    const float* __restrict__ bias, int K, int Nreal,
    void* out0_, void* out1_, void* out2_, const float* __restrict__ res) {
  __shared__ u16 As[BM * BK];
  __shared__ u16 Bs[BN * BK];
  const int tid = threadIdx.x;
  const int w = tid >> 6, lane = tid & 63;
  const int bm = blockIdx.y * BM, bn = blockIdx.x * BN;
  const int wr = (w >> 1) * 64, wc = (w & 1) * 64;

  const u16* Ag = A + (size_t)(bm + w * 32 + (lane >> 2)) * K + (lane & 3) * 8;
  const u16* Bg = Bt + (size_t)(bn + w * 32 + (lane >> 2)) * K + (lane & 3) * 8;
  char* lA = (char*)As + w * 2048;
  char* lB = (char*)Bs + w * 2048;

  f32x4 acc[4][4] = {};
  for (int k0 = 0; k0 < K; k0 += BK) {
    __syncthreads();
    gload_lds16(Ag, lA);
    gload_lds16(Ag + 16 * K, lA + 1024);
    gload_lds16(Bg, lB);
    gload_lds16(Bg + 16 * K, lB + 1024);
    Ag += BK; Bg += BK;
    __syncthreads();
    const int ka = (lane >> 4) * 8;
    const int lc = lane & 15;
    bf16x8 av[4], bv[4];
#pragma unroll
    for (int i = 0; i < 4; ++i) av[i] = *(const bf16x8*)&As[(wr + i * 16 + lc) * BK + ka];
#pragma unroll
    for (int j = 0; j < 4; ++j) bv[j] = *(const bf16x8*)&Bs[(wc + j * 16 + lc) * BK + ka];
#pragma unroll
    for (int i = 0; i < 4; ++i)
#pragma unroll
      for (int j = 0; j < 4; ++j)
        acc[i][j] = __builtin_amdgcn_mfma_f32_16x16x32_bf16(av[i], bv[j], acc[i][j], 0, 0, 0);
  }

  const int lr = (lane >> 4) * 4, lc = lane & 15;
#pragma unroll
  for (int i = 0; i < 4; ++i) {
#pragma unroll
    for (int j = 0; j < 4; ++j) {
      int col = bn + wc + j * 16 + lc;
      if (col >= Nreal) continue;
      float bb = bias ? bias[col] : 0.f;
#pragma unroll
      for (int r = 0; r < 4; ++r) {
        int row = bm + wr + i * 16 + lr + r;
        float c = acc[i][j][r] + bb;
        if constexpr (EP == EP_DKV) {
          u16* ckv = (u16*)out0_; float* nkv = (float*)out1_; float* kr = (float*)out2_;
          if (col < 512) { ckv[(size_t)row * 512 + col] = f2bf(c); nkv[(size_t)row * 576 + col] = c; }
          else kr[(size_t)row * 64 + (col - 512)] = c;
        }
      }
    }
  }
}

// ---------------- big GEMM: 128x256 tile, BK=64, 8 waves, dbuf -------------
// Single __syncthreads per K-step; stage of tile t+1 issued before compute of
// tile t (T3 minimum 2-phase). XCD-chunked swizzle: blocks with the same
// (blockIdx.x & 7) -> contiguous row-major tile range (nwg % 8 == 0 always).
template <int EP>
__global__ __launch_bounds__(512, 2) void k_gemm2(
    const u16* __restrict__ A, const u16* __restrict__ Bt,
    const float* __restrict__ bias, int K, int gx, int Nreal,
    void* out0_, void* out1_, const float* __restrict__ res) {
  __shared__ u16 As[2][128 * 64];
  __shared__ u16 Bs[2][256 * 64];
  const int tid = threadIdx.x;
  const int w = tid >> 6, lane = tid & 63;
  const int q8 = (int)gridDim.x >> 3;
  const int u = ((int)blockIdx.x & 7) * q8 + ((int)blockIdx.x >> 3);
  const int bn = (u % gx) * 256, bm = (u / gx) * 128;
  const int wr = (w >> 2) * 64, wc = (w & 3) * 64;
  const int lc = lane & 15, hi = lane >> 4;

  const u16* Ag = A + (size_t)(bm + (tid >> 3)) * K + (tid & 7) * 8;
  const u16* Bg = Bt + (size_t)(bn + (tid >> 3)) * K + (tid & 7) * 8;

  auto stage = [&](int buf, int k0) {
    char* lA = (char*)&As[buf][0] + tid * 16;
    char* lB = (char*)&Bs[buf][0] + tid * 16;
#pragma unroll
    for (int i = 0; i < 2; ++i)
      gload_lds16(Ag + (size_t)i * 64 * K + k0, lA + i * 8192);
#pragma unroll
    for (int i = 0; i < 4; ++i)
      gload_lds16(Bg + (size_t)i * 64 * K + k0, lB + i * 8192);
  };

  f32x4 acc[4][4] = {};
  const int NT = K >> 6;
  stage(0, 0);
  __syncthreads();
  int cur = 0;
  for (int t = 0; t < NT; ++t) {
    if (t + 1 < NT) stage(cur ^ 1, (t + 1) * 64);
#pragma unroll
    for (int ks = 0; ks < 2; ++ks) {
      bf16x8 av[4], bv[4];
#pragma unroll
      for (int mi = 0; mi < 4; ++mi)
        av[mi] = *(const bf16x8*)&As[cur][(wr + mi * 16 + lc) * 64 + ks * 32 + hi * 8];
#pragma unroll
      for (int ni = 0; ni < 4; ++ni)
        bv[ni] = *(const bf16x8*)&Bs[cur][(wc + ni * 16 + lc) * 64 + ks * 32 + hi * 8];
#pragma unroll
      for (int mi = 0; mi < 4; ++mi)
#pragma unroll
        for (int ni = 0; ni < 4; ++ni)
          acc[mi][ni] = __builtin_amdgcn_mfma_f32_16x16x32_bf16(av[mi], bv[ni], acc[mi][ni], 0, 0, 0);
    }
    __syncthreads();
    cur ^= 1;
  }

#pragma unroll
  for (int mi = 0; mi < 4; ++mi) {
#pragma unroll
    for (int ni = 0; ni < 4; ++ni) {
      int col = bn + wc + ni * 16 + lc;
      float bb = bias[col];
#pragma unroll
      for (int r = 0; r < 4; ++r) {
        int row = bm + wr + mi * 16 + hi * 4 + r;
        int b = row >> 11, s = row & 2047;
        float c = acc[mi][ni][r] + bb;
        if constexpr (EP == EP_Q) {
          u16* qall = (u16*)out0_; float* qr = (float*)out1_;
          int hh = col / 192, d = col - hh * 192;
          if (d < 128) qall[((size_t)(b * 16 + hh) * 2048 + s) * 192 + d] = f2bf(c);
          else qr[(size_t)row * 1024 + hh * 64 + (d - 128)] = c;
        } else if constexpr (EP == EP_KV) {
          u16* knb2h = (u16*)out0_; u16* vv = (u16*)out1_;
          int hh = col >> 8, d = col & 255;
          if (d < 128) knb2h[((size_t)(b * 16 + hh) * 2048 + s) * 128 + d] = f2bf(c);
          else vv[(size_t)row * 2048 + hh * 128 + (d - 128)] = f2bf(c);
        } else if constexpr (EP == EP_RES) {
          float* out = (float*)out0_;
          out[(size_t)row * Nreal + col] = res[(size_t)row * Nreal + col] + c;
        } else { // EP_GELU
          u16* g = (u16*)out0_;
          float gl = 0.5f * c * (1.f + erff(c * 0.70710678118f));
          g[(size_t)row * Nreal + col] = f2bf(gl);
        }
      }
    }
  }
}

// ---------------- Flash attention, register-prefetch pipelined -------------
#define QKS 200
#define VPS 72
__global__ __launch_bounds__(256, 2) void k_attn(
    const u16* __restrict__ qall, const u16* __restrict__ knb2h,
    const u16* __restrict__ krb_bf, const u16* __restrict__ vbT,
    u16* __restrict__ o) {
  __shared__ u16 Ks[64 * QKS];
  __shared__ u16 Vt[128 * VPS];
  __shared__ u16 Ps[64 * VPS];
  const int lin = blockIdx.x;
  const int qt = 31 - (lin >> 5);
  const int bh = (((lin >> 3) & 3) << 3) | (lin & 7);
  const int b = bh >> 4;
  const int tid = threadIdx.x, w = tid >> 6, lane = tid & 63;
  const float sc2 = 0.07216878365f * 1.4426950408f; // 1/sqrt(192) * log2(e)
  const int lr = (lane >> 4) * 4, lc = lane & 15, ka = (lane >> 4) * 8;

  bf16x8 qf[6];
  {
    const u16* qrow = qall + ((size_t)bh * 2048 + qt * 64 + w * 16 + lc) * 192;
#pragma unroll
    for (int ks = 0; ks < 6; ++ks) qf[ks] = *(const bf16x8*)&qrow[ks * 32 + ka];
  }

  const u16* gkn_base = knb2h + (size_t)bh * 2048 * 128;
  const u16* gkr_base = krb_bf + (size_t)b * 2048 * 64;
  const u16* gv_base = vbT + (size_t)bh * 128 * 2048;

  int4 kreg[6], vreg[4];
  auto loadT = [&](int t) {
    const u16* gkn = gkn_base + (size_t)t * 64 * 128;
    const u16* gkr = gkr_base + (size_t)t * 64 * 64;
#pragma unroll
    for (int k = 0; k < 4; ++k) kreg[k] = *(const int4*)(gkn + (tid + k * 256) * 8);
#pragma unroll
    for (int k = 0; k < 2; ++k) kreg[4 + k] = *(const int4*)(gkr + (tid + k * 256) * 8);
#pragma unroll
    for (int k = 0; k < 4; ++k) {
      int li = tid + k * 256, d = li >> 3, rb = li & 7;
      vreg[k] = *(const int4*)(gv_base + (size_t)d * 2048 + t * 64 + rb * 8);
    }
  };
  auto writeT = [&]() {
#pragma unroll
    for (int k = 0; k < 4; ++k) {
      int li = tid + k * 256, r = li >> 4, c = li & 15;
      *(int4*)((char*)Ks + r * 400 + c * 16) = kreg[k];
    }
#pragma unroll
    for (int k = 0; k < 2; ++k) {
      int li = tid + k * 256, r = li >> 3, c = li & 7;
      *(int4*)((char*)Ks + r * 400 + 256 + c * 16) = kreg[4 + k];
    }
#pragma unroll
    for (int k = 0; k < 4; ++k) {
      int li = tid + k * 256, d = li >> 3, rb = li & 7;
      *(int4*)((char*)Vt + d * 144 + rb * 16) = vreg[k];
    }
  };

  float m2[4] = {-1e30f, -1e30f, -1e30f, -1e30f};
  float l2[4] = {0.f, 0.f, 0.f, 0.f};
  f32x4 of[8] = {};

  loadT(0);
  for (int t = 0; t <= qt; ++t) {
    __builtin_amdgcn_s_barrier();
    writeT();
    if (t < qt) loadT(t + 1);
    asm volatile("s_waitcnt lgkmcnt(0)" ::: "memory");
    __builtin_amdgcn_s_barrier();
    __builtin_amdgcn_sched_barrier(0);

    f32x4 sf[4] = {};
    __builtin_amdgcn_s_setprio(1);
#pragma unroll
    for (int j = 0; j < 4; ++j) {
#pragma unroll
      for (int ks = 0; ks < 6; ++ks) {
        bf16x8 kf = *(const bf16x8*)&Ks[(j * 16 + lc) * QKS + ks * 32 + ka];
        sf[j] = __builtin_amdgcn_mfma_f32_16x16x32_bf16(qf[ks], kf, sf[j], 0, 0, 0);
      }
    }
    __builtin_amdgcn_s_setprio(0);

    float rm[4], fpr[4], ps[4];
#pragma unroll
    for (int j = 0; j < 4; ++j)
#pragma unroll
      for (int r = 0; r < 4; ++r) {
        float x_ = sf[j][r] * sc2;
        if (t == qt) {
          int colg = t * 64 + j * 16 + lc;
          int rowg = qt * 64 + w * 16 + lr + r;
          if (colg > rowg) x_ = -1e30f;
        }
        sf[j][r] = x_;
      }
#pragma unroll
    for (int r = 0; r < 4; ++r)
      rm[r] = fmaxf(fmaxf(sf[0][r], sf[1][r]), fmaxf(sf[2][r], sf[3][r]));
#pragma unroll
    for (int msk = 1; msk < 16; msk <<= 1)
#pragma unroll
      for (int r = 0; r < 4; ++r) rm[r] = fmaxf(rm[r], __shfl_xor(rm[r], msk));
#pragma unroll
    for (int r = 0; r < 4; ++r) {
      float mn = fmaxf(m2[r], rm[r]);
      fpr[r] = exp2f(m2[r] - mn);
      m2[r] = mn;
      ps[r] = 0.f;
    }
#pragma unroll
    for (int j = 0; j < 4; ++j)
#pragma unroll
      for (int r = 0; r < 4; ++r) {
        float p = exp2f(sf[j][r] - m2[r]);
        ps[r] += p;
        Ps[(w * 16 + lr + r) * VPS + j * 16 + lc] = f2bf(p);
      }
#pragma unroll
    for (int msk = 1; msk < 16; msk <<= 1)
#pragma unroll
      for (int r = 0; r < 4; ++r) ps[r] += __shfl_xor(ps[r], msk);
#pragma unroll
    for (int r = 0; r < 4; ++r) l2[r] = l2[r] * fpr[r] + ps[r];
#pragma unroll
    for (int nb = 0; nb < 8; ++nb)
#pragma unroll
      for (int r = 0; r < 4; ++r) of[nb][r] *= fpr[r];

    asm volatile("s_waitcnt lgkmcnt(0)" ::: "memory");
    __builtin_amdgcn_sched_barrier(0);

    __builtin_amdgcn_s_setprio(1);
#pragma unroll
    for (int ks = 0; ks < 2; ++ks) {
      bf16x8 ap = *(const bf16x8*)&Ps[(w * 16 + lc) * VPS + ks * 32 + ka];
#pragma unroll
      for (int nb = 0; nb < 8; ++nb) {
        bf16x8 bvv = *(const bf16x8*)&Vt[(nb * 16 + lc) * VPS + ks * 32 + ka];
        of[nb] = __builtin_amdgcn_mfma_f32_16x16x32_bf16(ap, bvv, of[nb], 0, 0, 0);
      }
    }
    __builtin_amdgcn_s_setprio(0);
  }

#pragma unroll
  for (int r = 0; r < 4; ++r) {
    float inv = 1.f / l2[r];
    size_t m = (size_t)(bh >> 4) * 2048 + (size_t)qt * 64 + w * 16 + lr + r;
#pragma unroll
    for (int nb = 0; nb < 8; ++nb)
      o[m * 2048 + (bh & 15) * 128 + nb * 16 + lc] = f2bf(of[nb][r] * inv);
  }
}

// ---------------- launch ----------------------------------------------------
extern "C" void kernel_launch(void* const* d_in, const int* in_sizes, int n_in,
                              void* d_out, int out_size, void* d_ws, size_t ws_size,
                              hipStream_t stream) {
  const float* x = (const float*)d_in[0];
  const float* ln1w = (const float*)d_in[1];
  const float* ln1b = (const float*)d_in[2];
  const float* ln2w = (const float*)d_in[3];
  const float* ln2b = (const float*)d_in[4];
  const float* wq = (const float*)d_in[5];
  const float* bq = (const float*)d_in[6];
  const float* wdkv = (const float*)d_in[7];
  const float* bdkv = (const float*)d_in[8];
  const float* wkv = (const float*)d_in[9];
  const float* bkv = (const float*)d_in[10];
  const float* wo = (const float*)d_in[11];
  const float* bo = (const float*)d_in[12];
  const float* w1 = (const float*)d_in[13];
  const float* b1 = (const float*)d_in[14];
  const float* w2 = (const float*)d_in[15];
  const float* b2 = (const float*)d_in[16];
  (void)in_sizes; (void)n_in; (void)out_size; (void)ws_size;

  char* ws = (char*)d_ws;
  size_t off = 0;
  auto alloc = [&](size_t bytes) { void* p = ws + off; off += (bytes + 255) & ~(size_t)255; return p; };

  u16* wqT = (u16*)alloc(3072ull * 2048 * 2);
  u16* wdkvT = (u16*)alloc(640ull * 2048 * 2);   // 576 real rows, padded to 640
  u16* wkvT = (u16*)alloc(4096ull * 512 * 2);
  u16* woT = (u16*)alloc(2048ull * 2048 * 2);
  u16* w1T = (u16*)alloc(8192ull * 2048 * 2);
  u16* w2T = (u16*)alloc(2048ull * 8192 * 2);
  u16* hbuf = (u16*)alloc(4096ull * 2048 * 2);   // LN1 out; reused for LN2 out
  float* cosT = (float*)alloc(2048ull * 32 * 4);
  float* sinT = (float*)alloc(2048ull * 32 * 4);
  u16* obuf = (u16*)alloc(4096ull * 2048 * 2);
  char* G0 = ws + off;                           // FFN g overlays the region below
  u16* qallb = (u16*)alloc(32ull * 2048 * 192 * 2);
  float* qrb = (float*)alloc(4096ull * 1024 * 4);
  u16* ckvb = (u16*)alloc(4096ull * 512 * 2);
  float* krb = (float*)alloc(4096ull * 64 * 4);
  u16* krb_bf = (u16*)alloc(4096ull * 64 * 2);
  u16* knb2h = (u16*)alloc(32ull * 2048 * 128 * 2);
  u16* vb = (u16*)alloc(4096ull * 2048 * 2);
  u16* vbT = (u16*)alloc(32ull * 128 * 2048 * 2);
  u16* gb = (u16*)G0;                            // 67.1MB <= region below (~98MB)

  float* xout = (float*)d_out;                   // [4096][2048]
  float* nkv = xout + 4096ull * 2048;            // [4096][576]

  dim3 blk(256);
  dim3 blk5(512);
  k_transpose_bf16<<<dim3(64, 96), blk, 0, stream>>>(wq, wqT, 2048, 3072);
  k_transpose_bf16<<<dim3(64, 18), blk, 0, stream>>>(wdkv, wdkvT, 2048, 576);
  k_transpose_bf16<<<dim3(16, 128), blk, 0, stream>>>(wkv, wkvT, 512, 4096);
  k_transpose_bf16<<<dim3(64, 64), blk, 0, stream>>>(wo, woT, 2048, 2048);
  k_transpose_bf16<<<dim3(64, 256), blk, 0, stream>>>(w1, w1T, 2048, 8192);
  k_transpose_bf16<<<dim3(256, 64), blk, 0, stream>>>(w2, w2T, 8192, 2048);
  k_rope_table<<<dim3(256), blk, 0, stream>>>(cosT, sinT);
  k_ln<<<dim3(4096), blk, 0, stream>>>(x, ln1w, ln1b, hbuf);
  // q: M=4096 N=3072 K=2048 -> grid 12*32=384
  k_gemm2<EP_Q><<<dim3(384), blk5, 0, stream>>>(hbuf, wqT, bq, 2048, 12, 3072, qallb, qrb, nullptr);
  k_gemm<EP_DKV><<<dim3(5, 32), blk, 0, stream>>>(hbuf, wdkvT, bdkv, 2048, 576, ckvb, nkv, krb, nullptr);
  k_rope_q<<<dim3(8192), blk, 0, stream>>>(qrb, cosT, sinT, qallb);
  k_rope_k<<<dim3(512), blk, 0, stream>>>(krb, cosT, sinT, nkv, krb_bf);
  // kv: M=4096 N=4096 K=512 -> grid 16*32=512
  k_gemm2<EP_KV><<<dim3(512), blk5, 0, stream>>>(ckvb, wkvT, bkv, 512, 16, 4096, knb2h, vb, nullptr);
  k_transpose_v<<<dim3(64, 4, 32), blk, 0, stream>>>(vb, vbT);
  k_attn<<<dim3(1024), blk, 0, stream>>>(qallb, knb2h, krb_bf, vbT, obuf);
  // o: M=4096 N=2048 K=2048 -> grid 8*32=256
  k_gemm2<EP_RES><<<dim3(256), blk5, 0, stream>>>(obuf, woT, bo, 2048, 8, 2048, xout, nullptr, x);
  k_ln<<<dim3(4096), blk, 0, stream>>>(xout, ln2w, ln2b, hbuf);
  // w1: M=4096 N=8192 K=2048 -> grid 32*32=1024
  k_gemm2<EP_GELU><<<dim3(1024), blk5, 0, stream>>>(hbuf, w1T, b1, 2048, 32, 8192, gb, nullptr, nullptr);
  // w2: M=4096 N=2048 K=8192 -> grid 8*32=256
  k_gemm2<EP_RES><<<dim3(256), blk5, 0, stream>>>(gb, w2T, b2, 8192, 8, 2048, xout, nullptr, xout);
}

// Round 7
// 841.784 us; speedup vs baseline: 1.7007x; 1.2069x over previous
//
#include <hip/hip_runtime.h>
#include <hip/hip_bf16.h>

// MLA transformer block on MI355X. Round 7:
// - attn: global_load_lds staging with pre-swizzled source (no reg transit,
//   no spill), K dbuf + V single buf, counted vmcnt, XOR bank swizzle.
// - gemm2: XOR source+read swizzle kills the 16-way BK=64 bank conflict.

typedef short bf16x8 __attribute__((ext_vector_type(8)));
typedef float f32x4 __attribute__((ext_vector_type(4)));
typedef unsigned short u16;

#define BM 128
#define BN 128
#define BK 32

__device__ __forceinline__ u16 f2bf(float f) {
  unsigned int u = __builtin_bit_cast(unsigned int, f);
  u += 0x7FFFu + ((u >> 16) & 1u);
  return (u16)(u >> 16);
}

__device__ __forceinline__ void gload_lds16(const void* g, void* l) {
  __builtin_amdgcn_global_load_lds(
      (const __attribute__((address_space(1))) unsigned int*)(uintptr_t)g,
      (__attribute__((address_space(3))) unsigned int*)(unsigned int)(uintptr_t)l,
      16, 0, 0);
}

// ---------------- transpose + f32->bf16 : out[N][K] = (bf16) in[K][N] ------
__global__ __launch_bounds__(256) void k_transpose_bf16(
    const float* __restrict__ in, u16* __restrict__ out, int K, int N) {
  __shared__ float tile[32][33];
  int k0 = blockIdx.x * 32, n0 = blockIdx.y * 32;
  int tx = threadIdx.x & 31, ty = threadIdx.x >> 5;
#pragma unroll
  for (int i = 0; i < 4; ++i) {
    int k = k0 + ty + i * 8, n = n0 + tx;
    tile[ty + i * 8][tx] = (k < K && n < N) ? in[(size_t)k * N + n] : 0.f;
  }
  __syncthreads();
#pragma unroll
  for (int i = 0; i < 4; ++i) {
    int n = n0 + ty + i * 8, k = k0 + tx;
    if (n < N && k < K) out[(size_t)n * K + k] = f2bf(tile[tx][ty + i * 8]);
  }
}

// ---------------- V transpose per (b,h): vb[m][h*128+d] -> vbT[bh][d][s] ----
__global__ __launch_bounds__(256) void k_transpose_v(
    const u16* __restrict__ vb, u16* __restrict__ vbT) {
  __shared__ u16 tile[32][34];
  int bh = blockIdx.z, b = bh >> 4, h = bh & 15;
  int s0 = blockIdx.x * 32, d0 = blockIdx.y * 32;
  int tx = threadIdx.x & 31, ty = threadIdx.x >> 5;
#pragma unroll
  for (int i = 0; i < 4; ++i)
    tile[ty + i * 8][tx] =
        vb[((size_t)b * 2048 + s0 + ty + i * 8) * 2048 + h * 128 + d0 + tx];
  __syncthreads();
#pragma unroll
  for (int i = 0; i < 4; ++i)
    vbT[((size_t)bh * 128 + d0 + ty + i * 8) * 2048 + s0 + tx] = tile[tx][ty + i * 8];
}

// ---------------- RoPE tables: cos/sin[s][i], i<32 -------------------------
__global__ void k_rope_table(float* __restrict__ cosT, float* __restrict__ sinT) {
  int idx = blockIdx.x * 256 + threadIdx.x;
  if (idx >= 2048 * 32) return;
  int s = idx >> 5, i = idx & 31;
  float inv = exp2f(-(float)i * 0.41524101186092037f); // log2(10000)/32
  float a = (float)s * inv;
  cosT[idx] = cosf(a);
  sinT[idx] = sinf(a);
}

// ---------------- LayerNorm row=2048, out bf16 -----------------------------
__global__ __launch_bounds__(256) void k_ln(const float* __restrict__ x,
                                            const float* __restrict__ w,
                                            const float* __restrict__ b,
                                            u16* __restrict__ out) {
  const int row = blockIdx.x, tid = threadIdx.x;
  const float* xr = x + (size_t)row * 2048;
  float xv[8];
  *(float4*)&xv[0] = ((const float4*)xr)[tid * 2];
  *(float4*)&xv[4] = ((const float4*)xr)[tid * 2 + 1];
  float s = 0.f, ss = 0.f;
#pragma unroll
  for (int j = 0; j < 8; ++j) { s += xv[j]; ss += xv[j] * xv[j]; }
#pragma unroll
  for (int m_ = 32; m_; m_ >>= 1) { s += __shfl_xor(s, m_); ss += __shfl_xor(ss, m_); }
  __shared__ float red[8];
  const int wv = tid >> 6;
  if ((tid & 63) == 0) { red[wv] = s; red[wv + 4] = ss; }
  __syncthreads();
  s = red[0] + red[1] + red[2] + red[3];
  ss = red[4] + red[5] + red[6] + red[7];
  const float mean = s * (1.f / 2048.f);
  const float rs = rsqrtf(ss * (1.f / 2048.f) - mean * mean + 1e-5f);
  float wv8[8], bv8[8];
  *(float4*)&wv8[0] = ((const float4*)w)[tid * 2];
  *(float4*)&wv8[4] = ((const float4*)w)[tid * 2 + 1];
  *(float4*)&bv8[0] = ((const float4*)b)[tid * 2];
  *(float4*)&bv8[4] = ((const float4*)b)[tid * 2 + 1];
  u16 t[8] __attribute__((aligned(16)));
#pragma unroll
  for (int j = 0; j < 8; ++j) t[j] = f2bf((xv[j] - mean) * rs * wv8[j] + bv8[j]);
  *(int4*)&out[(size_t)row * 2048 + tid * 8] = *(int4*)t;
}

// ---------------- RoPE: qr f32 -> qall bf16 (cols 128..191) ----------------
__global__ void k_rope_q(const float* __restrict__ qr, const float* __restrict__ cosT,
                         const float* __restrict__ sinT, u16* __restrict__ qall) {
  int idx = blockIdx.x * 256 + threadIdx.x; // 4096*16*32
  if (idx >= 4096 * 16 * 32) return;
  int i = idx & 31, rest = idx >> 5;
  int h = rest & 15, m = rest >> 4;
  int s = m & 2047, b = m >> 11;
  float c = cosT[s * 32 + i], sn = sinT[s * 32 + i];
  const float* p = qr + (size_t)m * 1024 + h * 64 + i;
  float x0 = p[0], x1 = p[32];
  u16* q = qall + ((size_t)(b * 16 + h) * 2048 + s) * 192 + 128 + i;
  q[0] = f2bf(x0 * c - x1 * sn);
  q[32] = f2bf(x1 * c + x0 * sn);
}

// ---------------- RoPE: kr f32 -> krb_bf bf16 + nkv f32 --------------------
__global__ void k_rope_k(const float* __restrict__ kr, const float* __restrict__ cosT,
                         const float* __restrict__ sinT, float* __restrict__ nkv,
                         u16* __restrict__ krb_bf) {
  int idx = blockIdx.x * 256 + threadIdx.x; // 4096*32
  if (idx >= 4096 * 32) return;
  int i = idx & 31, m = idx >> 5;
  int s = m & 2047;
  float c = cosT[s * 32 + i], sn = sinT[s * 32 + i];
  const float* p = kr + (size_t)m * 64 + i;
  float x0 = p[0], x1 = p[32];
  float y0 = x0 * c - x1 * sn;
  float y1 = x1 * c + x0 * sn;
  nkv[(size_t)m * 576 + 512 + i] = y0;
  nkv[(size_t)m * 576 + 544 + i] = y1;
  krb_bf[(size_t)m * 64 + i] = f2bf(y0);
  krb_bf[(size_t)m * 64 + 32 + i] = f2bf(y1);
}

enum { EP_Q = 0, EP_DKV = 1, EP_KV = 2, EP_RES = 3, EP_GELU = 4 };

// ---------------- small GEMM (dkv only): m97 128x128xBK32 ------------------
template <int EP>
__global__ __launch_bounds__(256) void k_gemm(
    const u16* __restrict__ A, const u16* __restrict__ Bt,
    const float* __restrict__ bias, int K, int Nreal,
    void* out0_, void* out1_, void* out2_, const float* __restrict__ res) {
  __shared__ u16 As[BM * BK];
  __shared__ u16 Bs[BN * BK];
  const int tid = threadIdx.x;
  const int w = tid >> 6, lane = tid & 63;
  const int bm = blockIdx.y * BM, bn = blockIdx.x * BN;
  const int wr = (w >> 1) * 64, wc = (w & 1) * 64;

  const u16* Ag = A + (size_t)(bm + w * 32 + (lane >> 2)) * K + (lane & 3) * 8;
  const u16* Bg = Bt + (size_t)(bn + w * 32 + (lane >> 2)) * K + (lane & 3) * 8;
  char* lA = (char*)As + w * 2048;
  char* lB = (char*)Bs + w * 2048;

  f32x4 acc[4][4] = {};
  for (int k0 = 0; k0 < K; k0 += BK) {
    __syncthreads();
    gload_lds16(Ag, lA);
    gload_lds16(Ag + 16 * K, lA + 1024);
    gload_lds16(Bg, lB);
    gload_lds16(Bg + 16 * K, lB + 1024);
    Ag += BK; Bg += BK;
    __syncthreads();
    const int ka = (lane >> 4) * 8;
    const int lc = lane & 15;
    bf16x8 av[4], bv[4];
#pragma unroll
    for (int i = 0; i < 4; ++i) av[i] = *(const bf16x8*)&As[(wr + i * 16 + lc) * BK + ka];
#pragma unroll
    for (int j = 0; j < 4; ++j) bv[j] = *(const bf16x8*)&Bs[(wc + j * 16 + lc) * BK + ka];
#pragma unroll
    for (int i = 0; i < 4; ++i)
#pragma unroll
      for (int j = 0; j < 4; ++j)
        acc[i][j] = __builtin_amdgcn_mfma_f32_16x16x32_bf16(av[i], bv[j], acc[i][j], 0, 0, 0);
  }

  const int lr = (lane >> 4) * 4, lc = lane & 15;
#pragma unroll
  for (int i = 0; i < 4; ++i) {
#pragma unroll
    for (int j = 0; j < 4; ++j) {
      int col = bn + wc + j * 16 + lc;
      if (col >= Nreal) continue;
      float bb = bias ? bias[col] : 0.f;
#pragma unroll
      for (int r = 0; r < 4; ++r) {
        int row = bm + wr + i * 16 + lr + r;
        float c = acc[i][j][r] + bb;
        if constexpr (EP == EP_DKV) {
          u16* ckv = (u16*)out0_; float* nkv = (float*)out1_; float* kr = (float*)out2_;
          if (col < 512) { ckv[(size_t)row * 512 + col] = f2bf(c); nkv[(size_t)row * 576 + col] = c; }
          else kr[(size_t)row * 64 + (col - 512)] = c;
        }
      }
    }
  }
}

// ---------------- big GEMM: 128x256 tile, BK=64, 8 waves, dbuf, XOR swz ----
// LDS rows are 128B (8 granules); source col-granule g is XORed with (row&7)
// on BOTH the staging source address and the fragment read -> 2-way (free).
template <int EP>
__global__ __launch_bounds__(512, 2) void k_gemm2(
    const u16* __restrict__ A, const u16* __restrict__ Bt,
    const float* __restrict__ bias, int K, int gx, int Nreal,
    void* out0_, void* out1_, const float* __restrict__ res) {
  __shared__ u16 As[2][128 * 64];
  __shared__ u16 Bs[2][256 * 64];
  const int tid = threadIdx.x;
  const int w = tid >> 6, lane = tid & 63;
  const int q8 = (int)gridDim.x >> 3;
  const int u = ((int)blockIdx.x & 7) * q8 + ((int)blockIdx.x >> 3);
  const int bn = (u % gx) * 256, bm = (u / gx) * 128;
  const int wr = (w >> 2) * 64, wc = (w & 3) * 64;
  const int lc = lane & 15, hi = lane >> 4;

  const int rowid = tid >> 3;                    // 0..63
  const int gsw = (tid & 7) ^ (rowid & 7);       // swizzled source granule
  const u16* Ag = A + (size_t)(bm + rowid) * K + gsw * 8;
  const u16* Bg = Bt + (size_t)(bn + rowid) * K + gsw * 8;

  auto stage = [&](int buf, int k0) {
    char* lA = (char*)&As[buf][0] + tid * 16;
    char* lB = (char*)&Bs[buf][0] + tid * 16;
#pragma unroll
    for (int i = 0; i < 2; ++i)
      gload_lds16(Ag + (size_t)i * 64 * K + k0, lA + i * 8192);
#pragma unroll
    for (int i = 0; i < 4; ++i)
      gload_lds16(Bg + (size_t)i * 64 * K + k0, lB + i * 8192);
  };

  f32x4 acc[4][4] = {};
  const int NT = K >> 6;
  stage(0, 0);
  __syncthreads();
  int cur = 0;
  for (int t = 0; t < NT; ++t) {
    if (t + 1 < NT) stage(cur ^ 1, (t + 1) * 64);
    const char* AsB = (const char*)&As[cur][0];
    const char* BsB = (const char*)&Bs[cur][0];
#pragma unroll
    for (int ks = 0; ks < 2; ++ks) {
      bf16x8 av[4], bv[4];
#pragma unroll
      for (int mi = 0; mi < 4; ++mi) {
        int row = wr + mi * 16 + lc;
        av[mi] = *(const bf16x8*)(AsB + row * 128 + (((ks * 4 + hi) ^ (row & 7)) << 4));
      }
#pragma unroll
      for (int ni = 0; ni < 4; ++ni) {
        int row = wc + ni * 16 + lc;
        bv[ni] = *(const bf16x8*)(BsB + row * 128 + (((ks * 4 + hi) ^ (row & 7)) << 4));
      }
#pragma unroll
      for (int mi = 0; mi < 4; ++mi)
#pragma unroll
        for (int ni = 0; ni < 4; ++ni)
          acc[mi][ni] = __builtin_amdgcn_mfma_f32_16x16x32_bf16(av[mi], bv[ni], acc[mi][ni], 0, 0, 0);
    }
    __syncthreads();
    cur ^= 1;
  }

#pragma unroll
  for (int mi = 0; mi < 4; ++mi) {
#pragma unroll
    for (int ni = 0; ni < 4; ++ni) {
      int col = bn + wc + ni * 16 + lc;
      float bb = bias[col];
#pragma unroll
      for (int r = 0; r < 4; ++r) {
        int row = bm + wr + mi * 16 + hi * 4 + r;
        int b = row >> 11, s = row & 2047;
        float c = acc[mi][ni][r] + bb;
        if constexpr (EP == EP_Q) {
          u16* qall = (u16*)out0_; float* qr = (float*)out1_;
          int hh = col / 192, d = col - hh * 192;
          if (d < 128) qall[((size_t)(b * 16 + hh) * 2048 + s) * 192 + d] = f2bf(c);
          else qr[(size_t)row * 1024 + hh * 64 + (d - 128)] = c;
        } else if constexpr (EP == EP_KV) {
          u16* knb2h = (u16*)out0_; u16* vv = (u16*)out1_;
          int hh = col >> 8, d = col & 255;
          if (d < 128) knb2h[((size_t)(b * 16 + hh) * 2048 + s) * 128 + d] = f2bf(c);
          else vv[(size_t)row * 2048 + hh * 128 + (d - 128)] = f2bf(c);
        } else if constexpr (EP == EP_RES) {
          float* out = (float*)out0_;
          out[(size_t)row * Nreal + col] = res[(size_t)row * Nreal + col] + c;
        } else { // EP_GELU
          u16* g = (u16*)out0_;
          float gl = 0.5f * c * (1.f + erff(c * 0.70710678118f));
          g[(size_t)row * Nreal + col] = f2bf(gl);
        }
      }
    }
  }
}

// ---------------- Flash attention: gload_lds staging, K dbuf, V single -----
// K tile: linear [64][192] u16 (384B rows, 24 granules) + granule XOR swz.
// V tile: linear [128][64] u16 (128B rows, 8 granules) + granule XOR swz.
// Per-lane pre-swizzled SOURCE addresses; LDS dest is linear (wave base +
// lane*16). Counted vmcnt(6) waits V only; K[t+1] stays in flight.
__global__ __launch_bounds__(256) void k_attn(
    const u16* __restrict__ qall, const u16* __restrict__ knb2h,
    const u16* __restrict__ krb_bf, const u16* __restrict__ vbT,
    u16* __restrict__ o) {
  __shared__ u16 Ks[2][64 * 192];  // 2 x 24576 B
  __shared__ u16 Vt[128 * 64];     // 16384 B
  __shared__ u16 Ps[64 * 72];      // 9216 B  (144B rows, 2-way free)
  const int lin = blockIdx.x;
  const int qt = 31 - (lin >> 5);
  const int bh = (((lin >> 3) & 3) << 3) | (lin & 7);
  const int b = bh >> 4;
  const int tid = threadIdx.x, w = tid >> 6, lane = tid & 63;
  const float sc2 = 0.07216878365f * 1.4426950408f; // 1/sqrt(192) * log2(e)
  const int lr = (lane >> 4) * 4, lc = lane & 15, ka = (lane >> 4) * 8;

  // ---- Q fragments in registers ----
  bf16x8 qf[6];
  {
    const u16* qrow = qall + ((size_t)bh * 2048 + qt * 64 + w * 16 + lc) * 192;
#pragma unroll
    for (int ks = 0; ks < 6; ++ks) qf[ks] = *(const bf16x8*)&qrow[ks * 32 + ka];
  }

  // ---- per-lane pre-swizzled staging source pointers ----
  const char* kp[6];
  int kstr[6];
  {
    const char* knB = (const char*)(knb2h + (size_t)bh * 2048 * 128);
    const char* krB = (const char*)(krb_bf + (size_t)b * 2048 * 64);
#pragma unroll
    for (int i = 0; i < 6; ++i) {
      int G = (i * 4 + w) * 64 + lane;   // dest granule 0..1535
      int row = G / 24, g = G - row * 24;
      int gs = g ^ (row & 7);            // stays within [0,16) or [16,24)
      if (gs < 16) { kp[i] = knB + row * 256 + gs * 16; kstr[i] = 16384; }
      else         { kp[i] = krB + row * 128 + (gs - 16) * 16; kstr[i] = 8192; }
    }
  }
  const char* vp[4];
  {
    const char* vB = (const char*)(vbT + (size_t)bh * 128 * 2048);
#pragma unroll
    for (int i = 0; i < 4; ++i) {
      int G = (i * 4 + w) * 64 + lane;   // dest granule 0..1023
      int d = G >> 3, g = G & 7;
      vp[i] = vB + d * 4096 + ((g ^ (d & 7)) << 4);
    }
  }

  // ---- prologue: stage K[0] into buf0 ----
#pragma unroll
  for (int i = 0; i < 6; ++i)
    gload_lds16(kp[i], (char*)&Ks[0][0] + (i * 4 + w) * 1024);
#pragma unroll
  for (int i = 0; i < 6; ++i) kp[i] += kstr[i];
  asm volatile("s_waitcnt vmcnt(0)" ::: "memory");
  __builtin_amdgcn_s_barrier();
  __builtin_amdgcn_sched_barrier(0);

  float m2[4] = {-1e30f, -1e30f, -1e30f, -1e30f};
  float l2[4] = {0.f, 0.f, 0.f, 0.f};
  f32x4 of[8] = {};
  int cur = 0;

  for (int t = 0; t <= qt; ++t) {
    // ---- stage V(t) (4 loads), then K[t+1] (6 loads) -- order pinned ----
#pragma unroll
    for (int i = 0; i < 4; ++i)
      gload_lds16(vp[i], (char*)Vt + (i * 4 + w) * 1024);
#pragma unroll
    for (int i = 0; i < 4; ++i) vp[i] += 128;
    __builtin_amdgcn_sched_barrier(0);
    if (t < qt) {
      char* kd = (char*)&Ks[cur ^ 1][0];
#pragma unroll
      for (int i = 0; i < 6; ++i)
        gload_lds16(kp[i], kd + (i * 4 + w) * 1024);
#pragma unroll
      for (int i = 0; i < 6; ++i) kp[i] += kstr[i];
    }
    __builtin_amdgcn_sched_barrier(0);

    // ---- QK^T from Ks[cur] (swizzled reads) ----
    const char* KsL = (const char*)&Ks[cur][0];
    f32x4 sf[4] = {};
    __builtin_amdgcn_s_setprio(1);
#pragma unroll
    for (int j = 0; j < 4; ++j) {
#pragma unroll
      for (int ks = 0; ks < 6; ++ks) {
        int row = j * 16 + lc;
        bf16x8 kf = *(const bf16x8*)(KsL + row * 384 + (((ks * 4 + (lane >> 4)) ^ (row & 7)) << 4));
        sf[j] = __builtin_amdgcn_mfma_f32_16x16x32_bf16(qf[ks], kf, sf[j], 0, 0, 0);
      }
    }
    __builtin_amdgcn_s_setprio(0);

    // ---- online softmax ----
    float rm[4], fpr[4], ps[4];
#pragma unroll
    for (int j = 0; j < 4; ++j)
#pragma unroll
      for (int r = 0; r < 4; ++r) {
        float x_ = sf[j][r] * sc2;
        if (t == qt) {
          int colg = t * 64 + j * 16 + lc;
          int rowg = qt * 64 + w * 16 + lr + r;
          if (colg > rowg) x_ = -1e30f;
        }
        sf[j][r] = x_;
      }
#pragma unroll
    for (int r = 0; r < 4; ++r)
      rm[r] = fmaxf(fmaxf(sf[0][r], sf[1][r]), fmaxf(sf[2][r], sf[3][r]));
#pragma unroll
    for (int msk = 1; msk < 16; msk <<= 1)
#pragma unroll
      for (int r = 0; r < 4; ++r) rm[r] = fmaxf(rm[r], __shfl_xor(rm[r], msk));
#pragma unroll
    for (int r = 0; r < 4; ++r) {
      float mn = fmaxf(m2[r], rm[r]);
      fpr[r] = exp2f(m2[r] - mn);
      m2[r] = mn;
      ps[r] = 0.f;
    }
#pragma unroll
    for (int j = 0; j < 4; ++j)
#pragma unroll
      for (int r = 0; r < 4; ++r) {
        float p = exp2f(sf[j][r] - m2[r]);
        ps[r] += p;
        Ps[(w * 16 + lr + r) * 72 + j * 16 + lc] = f2bf(p);
      }
#pragma unroll
    for (int msk = 1; msk < 16; msk <<= 1)
#pragma unroll
      for (int r = 0; r < 4; ++r) ps[r] += __shfl_xor(ps[r], msk);
#pragma unroll
    for (int r = 0; r < 4; ++r) l2[r] = l2[r] * fpr[r] + ps[r];
#pragma unroll
    for (int nb = 0; nb < 8; ++nb)
#pragma unroll
      for (int r = 0; r < 4; ++r) of[nb][r] *= fpr[r];

    // ---- wait V (oldest 4), keep K[t+1] in flight; barrier for visibility --
    if (t < qt) { asm volatile("s_waitcnt vmcnt(6)" ::: "memory"); }
    else        { asm volatile("s_waitcnt vmcnt(0)" ::: "memory"); }
    asm volatile("s_waitcnt lgkmcnt(0)" ::: "memory");
    __builtin_amdgcn_s_barrier();
    __builtin_amdgcn_sched_barrier(0);

    // ---- PV from Vt (swizzled reads) + Ps ----
    __builtin_amdgcn_s_setprio(1);
#pragma unroll
    for (int ks = 0; ks < 2; ++ks) {
      bf16x8 ap = *(const bf16x8*)&Ps[(w * 16 + lc) * 72 + ks * 32 + ka];
#pragma unroll
      for (int nb = 0; nb < 8; ++nb) {
        int d = nb * 16 + lc;
        bf16x8 bvv = *(const bf16x8*)((const char*)Vt + d * 128 + (((ks * 4 + (lane >> 4)) ^ (d & 7)) << 4));
        of[nb] = __builtin_amdgcn_mfma_f32_16x16x32_bf16(ap, bvv, of[nb], 0, 0, 0);
      }
    }
    __builtin_amdgcn_s_setprio(0);

    // ---- drain K[t+1]; barrier gates next V overwrite + K buffer reuse ----
    asm volatile("s_waitcnt vmcnt(0)" ::: "memory");
    __builtin_amdgcn_s_barrier();
    __builtin_amdgcn_sched_barrier(0);
    cur ^= 1;
  }

#pragma unroll
  for (int r = 0; r < 4; ++r) {
    float inv = 1.f / l2[r];
    size_t m = (size_t)(bh >> 4) * 2048 + (size_t)qt * 64 + w * 16 + lr + r;
#pragma unroll
    for (int nb = 0; nb < 8; ++nb)
      o[m * 2048 + (bh & 15) * 128 + nb * 16 + lc] = f2bf(of[nb][r] * inv);
  }
}

// ---------------- launch ----------------------------------------------------
extern "C" void kernel_launch(void* const* d_in, const int* in_sizes, int n_in,
                              void* d_out, int out_size, void* d_ws, size_t ws_size,
                              hipStream_t stream) {
  const float* x = (const float*)d_in[0];
  const float* ln1w = (const float*)d_in[1];
  const float* ln1b = (const float*)d_in[2];
  const float* ln2w = (const float*)d_in[3];
  const float* ln2b = (const float*)d_in[4];
  const float* wq = (const float*)d_in[5];
  const float* bq = (const float*)d_in[6];
  const float* wdkv = (const float*)d_in[7];
  const float* bdkv = (const float*)d_in[8];
  const float* wkv = (const float*)d_in[9];
  const float* bkv = (const float*)d_in[10];
  const float* wo = (const float*)d_in[11];
  const float* bo = (const float*)d_in[12];
  const float* w1 = (const float*)d_in[13];
  const float* b1 = (const float*)d_in[14];
  const float* w2 = (const float*)d_in[15];
  const float* b2 = (const float*)d_in[16];
  (void)in_sizes; (void)n_in; (void)out_size; (void)ws_size;

  char* ws = (char*)d_ws;
  size_t off = 0;
  auto alloc = [&](size_t bytes) { void* p = ws + off; off += (bytes + 255) & ~(size_t)255; return p; };

  u16* wqT = (u16*)alloc(3072ull * 2048 * 2);
  u16* wdkvT = (u16*)alloc(640ull * 2048 * 2);   // 576 real rows, padded to 640
  u16* wkvT = (u16*)alloc(4096ull * 512 * 2);
  u16* woT = (u16*)alloc(2048ull * 2048 * 2);
  u16* w1T = (u16*)alloc(8192ull * 2048 * 2);
  u16* w2T = (u16*)alloc(2048ull * 8192 * 2);
  u16* hbuf = (u16*)alloc(4096ull * 2048 * 2);   // LN1 out; reused for LN2 out
  float* cosT = (float*)alloc(2048ull * 32 * 4);
  float* sinT = (float*)alloc(2048ull * 32 * 4);
  u16* obuf = (u16*)alloc(4096ull * 2048 * 2);
  char* G0 = ws + off;                           // FFN g overlays the region below
  u16* qallb = (u16*)alloc(32ull * 2048 * 192 * 2);
  float* qrb = (float*)alloc(4096ull * 1024 * 4);
  u16* ckvb = (u16*)alloc(4096ull * 512 * 2);
  float* krb = (float*)alloc(4096ull * 64 * 4);
  u16* krb_bf = (u16*)alloc(4096ull * 64 * 2);
  u16* knb2h = (u16*)alloc(32ull * 2048 * 128 * 2);
  u16* vb = (u16*)alloc(4096ull * 2048 * 2);
  u16* vbT = (u16*)alloc(32ull * 128 * 2048 * 2);
  u16* gb = (u16*)G0;                            // 67.1MB <= region below (~98MB)

  float* xout = (float*)d_out;                   // [4096][2048]
  float* nkv = xout + 4096ull * 2048;            // [4096][576]

  dim3 blk(256);
  dim3 blk5(512);
  k_transpose_bf16<<<dim3(64, 96), blk, 0, stream>>>(wq, wqT, 2048, 3072);
  k_transpose_bf16<<<dim3(64, 18), blk, 0, stream>>>(wdkv, wdkvT, 2048, 576);
  k_transpose_bf16<<<dim3(16, 128), blk, 0, stream>>>(wkv, wkvT, 512, 4096);
  k_transpose_bf16<<<dim3(64, 64), blk, 0, stream>>>(wo, woT, 2048, 2048);
  k_transpose_bf16<<<dim3(64, 256), blk, 0, stream>>>(w1, w1T, 2048, 8192);
  k_transpose_bf16<<<dim3(256, 64), blk, 0, stream>>>(w2, w2T, 8192, 2048);
  k_rope_table<<<dim3(256), blk, 0, stream>>>(cosT, sinT);
  k_ln<<<dim3(4096), blk, 0, stream>>>(x, ln1w, ln1b, hbuf);
  // q: M=4096 N=3072 K=2048 -> grid 12*32=384
  k_gemm2<EP_Q><<<dim3(384), blk5, 0, stream>>>(hbuf, wqT, bq, 2048, 12, 3072, qallb, qrb, nullptr);
  k_gemm<EP_DKV><<<dim3(5, 32), blk, 0, stream>>>(hbuf, wdkvT, bdkv, 2048, 576, ckvb, nkv, krb, nullptr);
  k_rope_q<<<dim3(8192), blk, 0, stream>>>(qrb, cosT, sinT, qallb);
  k_rope_k<<<dim3(512), blk, 0, stream>>>(krb, cosT, sinT, nkv, krb_bf);
  // kv: M=4096 N=4096 K=512 -> grid 16*32=512
  k_gemm2<EP_KV><<<dim3(512), blk5, 0, stream>>>(ckvb, wkvT, bkv, 512, 16, 4096, knb2h, vb, nullptr);
  k_transpose_v<<<dim3(64, 4, 32), blk, 0, stream>>>(vb, vbT);
  k_attn<<<dim3(1024), blk, 0, stream>>>(qallb, knb2h, krb_bf, vbT, obuf);
  // o: M=4096 N=2048 K=2048 -> grid 8*32=256
  k_gemm2<EP_RES><<<dim3(256), blk5, 0, stream>>>(obuf, woT, bo, 2048, 8, 2048, xout, nullptr, x);
  k_ln<<<dim3(4096), blk, 0, stream>>>(xout, ln2w, ln2b, hbuf);
  // w1: M=4096 N=8192 K=2048 -> grid 32*32=1024
  k_gemm2<EP_GELU><<<dim3(1024), blk5, 0, stream>>>(hbuf, w1T, b1, 2048, 32, 8192, gb, nullptr, nullptr);
  // w2: M=4096 N=2048 K=8192 -> grid 8*32=256
  k_gemm2<EP_RES><<<dim3(256), blk5, 0, stream>>>(gb, w2T, b2, 8192, 8, 2048, xout, nullptr, xout);
}

// Round 8
// 802.440 us; speedup vs baseline: 1.7841x; 1.0490x over previous
//
#include <hip/hip_runtime.h>
#include <hip/hip_bf16.h>

// MLA transformer block on MI355X. Round 8: gemm2 T4 upgrade -- counted
// vmcnt(6) + raw s_barriers so next-tile loads stay in flight across the
// barrier (no vmcnt(0) drain in the main loop). Attn unchanged.

typedef short bf16x8 __attribute__((ext_vector_type(8)));
typedef float f32x4 __attribute__((ext_vector_type(4)));
typedef unsigned short u16;

#define BM 128
#define BN 128
#define BK 32

__device__ __forceinline__ u16 f2bf(float f) {
  unsigned int u = __builtin_bit_cast(unsigned int, f);
  u += 0x7FFFu + ((u >> 16) & 1u);
  return (u16)(u >> 16);
}

__device__ __forceinline__ void gload_lds16(const void* g, void* l) {
  __builtin_amdgcn_global_load_lds(
      (const __attribute__((address_space(1))) unsigned int*)(uintptr_t)g,
      (__attribute__((address_space(3))) unsigned int*)(unsigned int)(uintptr_t)l,
      16, 0, 0);
}

// ---------------- transpose + f32->bf16 : out[N][K] = (bf16) in[K][N] ------
__global__ __launch_bounds__(256) void k_transpose_bf16(
    const float* __restrict__ in, u16* __restrict__ out, int K, int N) {
  __shared__ float tile[32][33];
  int k0 = blockIdx.x * 32, n0 = blockIdx.y * 32;
  int tx = threadIdx.x & 31, ty = threadIdx.x >> 5;
#pragma unroll
  for (int i = 0; i < 4; ++i) {
    int k = k0 + ty + i * 8, n = n0 + tx;
    tile[ty + i * 8][tx] = (k < K && n < N) ? in[(size_t)k * N + n] : 0.f;
  }
  __syncthreads();
#pragma unroll
  for (int i = 0; i < 4; ++i) {
    int n = n0 + ty + i * 8, k = k0 + tx;
    if (n < N && k < K) out[(size_t)n * K + k] = f2bf(tile[tx][ty + i * 8]);
  }
}

// ---------------- V transpose per (b,h): vb[m][h*128+d] -> vbT[bh][d][s] ----
__global__ __launch_bounds__(256) void k_transpose_v(
    const u16* __restrict__ vb, u16* __restrict__ vbT) {
  __shared__ u16 tile[32][34];
  int bh = blockIdx.z, b = bh >> 4, h = bh & 15;
  int s0 = blockIdx.x * 32, d0 = blockIdx.y * 32;
  int tx = threadIdx.x & 31, ty = threadIdx.x >> 5;
#pragma unroll
  for (int i = 0; i < 4; ++i)
    tile[ty + i * 8][tx] =
        vb[((size_t)b * 2048 + s0 + ty + i * 8) * 2048 + h * 128 + d0 + tx];
  __syncthreads();
#pragma unroll
  for (int i = 0; i < 4; ++i)
    vbT[((size_t)bh * 128 + d0 + ty + i * 8) * 2048 + s0 + tx] = tile[tx][ty + i * 8];
}

// ---------------- RoPE tables: cos/sin[s][i], i<32 -------------------------
__global__ void k_rope_table(float* __restrict__ cosT, float* __restrict__ sinT) {
  int idx = blockIdx.x * 256 + threadIdx.x;
  if (idx >= 2048 * 32) return;
  int s = idx >> 5, i = idx & 31;
  float inv = exp2f(-(float)i * 0.41524101186092037f); // log2(10000)/32
  float a = (float)s * inv;
  cosT[idx] = cosf(a);
  sinT[idx] = sinf(a);
}

// ---------------- LayerNorm row=2048, out bf16 -----------------------------
__global__ __launch_bounds__(256) void k_ln(const float* __restrict__ x,
                                            const float* __restrict__ w,
                                            const float* __restrict__ b,
                                            u16* __restrict__ out) {
  const int row = blockIdx.x, tid = threadIdx.x;
  const float* xr = x + (size_t)row * 2048;
  float xv[8];
  *(float4*)&xv[0] = ((const float4*)xr)[tid * 2];
  *(float4*)&xv[4] = ((const float4*)xr)[tid * 2 + 1];
  float s = 0.f, ss = 0.f;
#pragma unroll
  for (int j = 0; j < 8; ++j) { s += xv[j]; ss += xv[j] * xv[j]; }
#pragma unroll
  for (int m_ = 32; m_; m_ >>= 1) { s += __shfl_xor(s, m_); ss += __shfl_xor(ss, m_); }
  __shared__ float red[8];
  const int wv = tid >> 6;
  if ((tid & 63) == 0) { red[wv] = s; red[wv + 4] = ss; }
  __syncthreads();
  s = red[0] + red[1] + red[2] + red[3];
  ss = red[4] + red[5] + red[6] + red[7];
  const float mean = s * (1.f / 2048.f);
  const float rs = rsqrtf(ss * (1.f / 2048.f) - mean * mean + 1e-5f);
  float wv8[8], bv8[8];
  *(float4*)&wv8[0] = ((const float4*)w)[tid * 2];
  *(float4*)&wv8[4] = ((const float4*)w)[tid * 2 + 1];
  *(float4*)&bv8[0] = ((const float4*)b)[tid * 2];
  *(float4*)&bv8[4] = ((const float4*)b)[tid * 2 + 1];
  u16 t[8] __attribute__((aligned(16)));
#pragma unroll
  for (int j = 0; j < 8; ++j) t[j] = f2bf((xv[j] - mean) * rs * wv8[j] + bv8[j]);
  *(int4*)&out[(size_t)row * 2048 + tid * 8] = *(int4*)t;
}

// ---------------- RoPE: qr f32 -> qall bf16 (cols 128..191) ----------------
__global__ void k_rope_q(const float* __restrict__ qr, const float* __restrict__ cosT,
                         const float* __restrict__ sinT, u16* __restrict__ qall) {
  int idx = blockIdx.x * 256 + threadIdx.x; // 4096*16*32
  if (idx >= 4096 * 16 * 32) return;
  int i = idx & 31, rest = idx >> 5;
  int h = rest & 15, m = rest >> 4;
  int s = m & 2047, b = m >> 11;
  float c = cosT[s * 32 + i], sn = sinT[s * 32 + i];
  const float* p = qr + (size_t)m * 1024 + h * 64 + i;
  float x0 = p[0], x1 = p[32];
  u16* q = qall + ((size_t)(b * 16 + h) * 2048 + s) * 192 + 128 + i;
  q[0] = f2bf(x0 * c - x1 * sn);
  q[32] = f2bf(x1 * c + x0 * sn);
}

// ---------------- RoPE: kr f32 -> krb_bf bf16 + nkv f32 --------------------
__global__ void k_rope_k(const float* __restrict__ kr, const float* __restrict__ cosT,
                         const float* __restrict__ sinT, float* __restrict__ nkv,
                         u16* __restrict__ krb_bf) {
  int idx = blockIdx.x * 256 + threadIdx.x; // 4096*32
  if (idx >= 4096 * 32) return;
  int i = idx & 31, m = idx >> 5;
  int s = m & 2047;
  float c = cosT[s * 32 + i], sn = sinT[s * 32 + i];
  const float* p = kr + (size_t)m * 64 + i;
  float x0 = p[0], x1 = p[32];
  float y0 = x0 * c - x1 * sn;
  float y1 = x1 * c + x0 * sn;
  nkv[(size_t)m * 576 + 512 + i] = y0;
  nkv[(size_t)m * 576 + 544 + i] = y1;
  krb_bf[(size_t)m * 64 + i] = f2bf(y0);
  krb_bf[(size_t)m * 64 + 32 + i] = f2bf(y1);
}

enum { EP_Q = 0, EP_DKV = 1, EP_KV = 2, EP_RES = 3, EP_GELU = 4 };

// ---------------- small GEMM (dkv only): m97 128x128xBK32 ------------------
template <int EP>
__global__ __launch_bounds__(256) void k_gemm(
    const u16* __restrict__ A, const u16* __restrict__ Bt,
    const float* __restrict__ bias, int K, int Nreal,
    void* out0_, void* out1_, void* out2_, const float* __restrict__ res) {
  __shared__ u16 As[BM * BK];
  __shared__ u16 Bs[BN * BK];
  const int tid = threadIdx.x;
  const int w = tid >> 6, lane = tid & 63;
  const int bm = blockIdx.y * BM, bn = blockIdx.x * BN;
  const int wr = (w >> 1) * 64, wc = (w & 1) * 64;

  const u16* Ag = A + (size_t)(bm + w * 32 + (lane >> 2)) * K + (lane & 3) * 8;
  const u16* Bg = Bt + (size_t)(bn + w * 32 + (lane >> 2)) * K + (lane & 3) * 8;
  char* lA = (char*)As + w * 2048;
  char* lB = (char*)Bs + w * 2048;

  f32x4 acc[4][4] = {};
  for (int k0 = 0; k0 < K; k0 += BK) {
    __syncthreads();
    gload_lds16(Ag, lA);
    gload_lds16(Ag + 16 * K, lA + 1024);
    gload_lds16(Bg, lB);
    gload_lds16(Bg + 16 * K, lB + 1024);
    Ag += BK; Bg += BK;
    __syncthreads();
    const int ka = (lane >> 4) * 8;
    const int lc = lane & 15;
    bf16x8 av[4], bv[4];
#pragma unroll
    for (int i = 0; i < 4; ++i) av[i] = *(const bf16x8*)&As[(wr + i * 16 + lc) * BK + ka];
#pragma unroll
    for (int j = 0; j < 4; ++j) bv[j] = *(const bf16x8*)&Bs[(wc + j * 16 + lc) * BK + ka];
#pragma unroll
    for (int i = 0; i < 4; ++i)
#pragma unroll
      for (int j = 0; j < 4; ++j)
        acc[i][j] = __builtin_amdgcn_mfma_f32_16x16x32_bf16(av[i], bv[j], acc[i][j], 0, 0, 0);
  }

  const int lr = (lane >> 4) * 4, lc = lane & 15;
#pragma unroll
  for (int i = 0; i < 4; ++i) {
#pragma unroll
    for (int j = 0; j < 4; ++j) {
      int col = bn + wc + j * 16 + lc;
      if (col >= Nreal) continue;
      float bb = bias ? bias[col] : 0.f;
#pragma unroll
      for (int r = 0; r < 4; ++r) {
        int row = bm + wr + i * 16 + lr + r;
        float c = acc[i][j][r] + bb;
        if constexpr (EP == EP_DKV) {
          u16* ckv = (u16*)out0_; float* nkv = (float*)out1_; float* kr = (float*)out2_;
          if (col < 512) { ckv[(size_t)row * 512 + col] = f2bf(c); nkv[(size_t)row * 576 + col] = c; }
          else kr[(size_t)row * 64 + (col - 512)] = c;
        }
      }
    }
  }
}

// ---------------- big GEMM: 128x256 tile, BK=64, 8 waves, dbuf, XOR swz ----
// T4: counted vmcnt(6) + raw barriers -- next tile's 6 loads stay in flight
// across the barrier and the whole compute phase; never drained mid-loop.
template <int EP>
__global__ __launch_bounds__(512, 2) void k_gemm2(
    const u16* __restrict__ A, const u16* __restrict__ Bt,
    const float* __restrict__ bias, int K, int gx, int Nreal,
    void* out0_, void* out1_, const float* __restrict__ res) {
  __shared__ u16 As[2][128 * 64];
  __shared__ u16 Bs[2][256 * 64];
  const int tid = threadIdx.x;
  const int w = tid >> 6, lane = tid & 63;
  const int q8 = (int)gridDim.x >> 3;
  const int u = ((int)blockIdx.x & 7) * q8 + ((int)blockIdx.x >> 3);
  const int bn = (u % gx) * 256, bm = (u / gx) * 128;
  const int wr = (w >> 2) * 64, wc = (w & 3) * 64;
  const int lc = lane & 15, hi = lane >> 4;

  const int rowid = tid >> 3;                    // 0..63
  const int gsw = (tid & 7) ^ (rowid & 7);       // swizzled source granule
  const u16* Ag = A + (size_t)(bm + rowid) * K + gsw * 8;
  const u16* Bg = Bt + (size_t)(bn + rowid) * K + gsw * 8;

  auto stage = [&](int buf, int k0) {
    char* lA = (char*)&As[buf][0] + tid * 16;
    char* lB = (char*)&Bs[buf][0] + tid * 16;
#pragma unroll
    for (int i = 0; i < 2; ++i)
      gload_lds16(Ag + (size_t)i * 64 * K + k0, lA + i * 8192);
#pragma unroll
    for (int i = 0; i < 4; ++i)
      gload_lds16(Bg + (size_t)i * 64 * K + k0, lB + i * 8192);
  };

  f32x4 acc[4][4] = {};
  const int NT = K >> 6;
  stage(0, 0);
  for (int t = 0; t < NT; ++t) {
    if (t + 1 < NT) {
      stage((t + 1) & 1, (t + 1) * 64);
      asm volatile("s_waitcnt vmcnt(6)" ::: "memory");   // tile t landed
    } else {
      asm volatile("s_waitcnt vmcnt(0)" ::: "memory");
    }
    __builtin_amdgcn_s_barrier();                        // visible to all waves
    __builtin_amdgcn_sched_barrier(0);
    const char* AsB = (const char*)&As[t & 1][0];
    const char* BsB = (const char*)&Bs[t & 1][0];
#pragma unroll
    for (int ks = 0; ks < 2; ++ks) {
      bf16x8 av[4], bv[4];
#pragma unroll
      for (int mi = 0; mi < 4; ++mi) {
        int row = wr + mi * 16 + lc;
        av[mi] = *(const bf16x8*)(AsB + row * 128 + (((ks * 4 + hi) ^ (row & 7)) << 4));
      }
#pragma unroll
      for (int ni = 0; ni < 4; ++ni) {
        int row = wc + ni * 16 + lc;
        bv[ni] = *(const bf16x8*)(BsB + row * 128 + (((ks * 4 + hi) ^ (row & 7)) << 4));
      }
#pragma unroll
      for (int mi = 0; mi < 4; ++mi)
#pragma unroll
        for (int ni = 0; ni < 4; ++ni)
          acc[mi][ni] = __builtin_amdgcn_mfma_f32_16x16x32_bf16(av[mi], bv[ni], acc[mi][ni], 0, 0, 0);
    }
    asm volatile("s_waitcnt lgkmcnt(0)" ::: "memory");   // ds_reads done
    __builtin_amdgcn_s_barrier();                        // safe to overwrite buf
  }

#pragma unroll
  for (int mi = 0; mi < 4; ++mi) {
#pragma unroll
    for (int ni = 0; ni < 4; ++ni) {
      int col = bn + wc + ni * 16 + lc;
      float bb = bias[col];
#pragma unroll
      for (int r = 0; r < 4; ++r) {
        int row = bm + wr + mi * 16 + hi * 4 + r;
        int b = row >> 11, s = row & 2047;
        float c = acc[mi][ni][r] + bb;
        if constexpr (EP == EP_Q) {
          u16* qall = (u16*)out0_; float* qr = (float*)out1_;
          int hh = col / 192, d = col - hh * 192;
          if (d < 128) qall[((size_t)(b * 16 + hh) * 2048 + s) * 192 + d] = f2bf(c);
          else qr[(size_t)row * 1024 + hh * 64 + (d - 128)] = c;
        } else if constexpr (EP == EP_KV) {
          u16* knb2h = (u16*)out0_; u16* vv = (u16*)out1_;
          int hh = col >> 8, d = col & 255;
          if (d < 128) knb2h[((size_t)(b * 16 + hh) * 2048 + s) * 128 + d] = f2bf(c);
          else vv[(size_t)row * 2048 + hh * 128 + (d - 128)] = f2bf(c);
        } else if constexpr (EP == EP_RES) {
          float* out = (float*)out0_;
          out[(size_t)row * Nreal + col] = res[(size_t)row * Nreal + col] + c;
        } else { // EP_GELU
          u16* g = (u16*)out0_;
          float gl = 0.5f * c * (1.f + erff(c * 0.70710678118f));
          g[(size_t)row * Nreal + col] = f2bf(gl);
        }
      }
    }
  }
}

// ---------------- Flash attention: gload_lds staging, K dbuf, V single -----
__global__ __launch_bounds__(256) void k_attn(
    const u16* __restrict__ qall, const u16* __restrict__ knb2h,
    const u16* __restrict__ krb_bf, const u16* __restrict__ vbT,
    u16* __restrict__ o) {
  __shared__ u16 Ks[2][64 * 192];  // 2 x 24576 B
  __shared__ u16 Vt[128 * 64];     // 16384 B
  __shared__ u16 Ps[64 * 72];      // 9216 B  (144B rows, 2-way free)
  const int lin = blockIdx.x;
  const int qt = 31 - (lin >> 5);
  const int bh = (((lin >> 3) & 3) << 3) | (lin & 7);
  const int b = bh >> 4;
  const int tid = threadIdx.x, w = tid >> 6, lane = tid & 63;
  const float sc2 = 0.07216878365f * 1.4426950408f; // 1/sqrt(192) * log2(e)
  const int lr = (lane >> 4) * 4, lc = lane & 15, ka = (lane >> 4) * 8;

  bf16x8 qf[6];
  {
    const u16* qrow = qall + ((size_t)bh * 2048 + qt * 64 + w * 16 + lc) * 192;
#pragma unroll
    for (int ks = 0; ks < 6; ++ks) qf[ks] = *(const bf16x8*)&qrow[ks * 32 + ka];
  }

  const char* kp[6];
  int kstr[6];
  {
    const char* knB = (const char*)(knb2h + (size_t)bh * 2048 * 128);
    const char* krB = (const char*)(krb_bf + (size_t)b * 2048 * 64);
#pragma unroll
    for (int i = 0; i < 6; ++i) {
      int G = (i * 4 + w) * 64 + lane;
      int row = G / 24, g = G - row * 24;
      int gs = g ^ (row & 7);
      if (gs < 16) { kp[i] = knB + row * 256 + gs * 16; kstr[i] = 16384; }
      else         { kp[i] = krB + row * 128 + (gs - 16) * 16; kstr[i] = 8192; }
    }
  }
  const char* vp[4];
  {
    const char* vB = (const char*)(vbT + (size_t)bh * 128 * 2048);
#pragma unroll
    for (int i = 0; i < 4; ++i) {
      int G = (i * 4 + w) * 64 + lane;
      int d = G >> 3, g = G & 7;
      vp[i] = vB + d * 4096 + ((g ^ (d & 7)) << 4);
    }
  }

#pragma unroll
  for (int i = 0; i < 6; ++i)
    gload_lds16(kp[i], (char*)&Ks[0][0] + (i * 4 + w) * 1024);
#pragma unroll
  for (int i = 0; i < 6; ++i) kp[i] += kstr[i];
  asm volatile("s_waitcnt vmcnt(0)" ::: "memory");
  __builtin_amdgcn_s_barrier();
  __builtin_amdgcn_sched_barrier(0);

  float m2[4] = {-1e30f, -1e30f, -1e30f, -1e30f};
  float l2[4] = {0.f, 0.f, 0.f, 0.f};
  f32x4 of[8] = {};
  int cur = 0;

  for (int t = 0; t <= qt; ++t) {
#pragma unroll
    for (int i = 0; i < 4; ++i)
      gload_lds16(vp[i], (char*)Vt + (i * 4 + w) * 1024);
#pragma unroll
    for (int i = 0; i < 4; ++i) vp[i] += 128;
    __builtin_amdgcn_sched_barrier(0);
    if (t < qt) {
      char* kd = (char*)&Ks[cur ^ 1][0];
#pragma unroll
      for (int i = 0; i < 6; ++i)
        gload_lds16(kp[i], kd + (i * 4 + w) * 1024);
#pragma unroll
      for (int i = 0; i < 6; ++i) kp[i] += kstr[i];
    }
    __builtin_amdgcn_sched_barrier(0);

    const char* KsL = (const char*)&Ks[cur][0];
    f32x4 sf[4] = {};
    __builtin_amdgcn_s_setprio(1);
#pragma unroll
    for (int j = 0; j < 4; ++j) {
#pragma unroll
      for (int ks = 0; ks < 6; ++ks) {
        int row = j * 16 + lc;
        bf16x8 kf = *(const bf16x8*)(KsL + row * 384 + (((ks * 4 + (lane >> 4)) ^ (row & 7)) << 4));
        sf[j] = __builtin_amdgcn_mfma_f32_16x16x32_bf16(qf[ks], kf, sf[j], 0, 0, 0);
      }
    }
    __builtin_amdgcn_s_setprio(0);

    float rm[4], fpr[4], ps[4];
#pragma unroll
    for (int j = 0; j < 4; ++j)
#pragma unroll
      for (int r = 0; r < 4; ++r) {
        float x_ = sf[j][r] * sc2;
        if (t == qt) {
          int colg = t * 64 + j * 16 + lc;
          int rowg = qt * 64 + w * 16 + lr + r;
          if (colg > rowg) x_ = -1e30f;
        }
        sf[j][r] = x_;
      }
#pragma unroll
    for (int r = 0; r < 4; ++r)
      rm[r] = fmaxf(fmaxf(sf[0][r], sf[1][r]), fmaxf(sf[2][r], sf[3][r]));
#pragma unroll
    for (int msk = 1; msk < 16; msk <<= 1)
#pragma unroll
      for (int r = 0; r < 4; ++r) rm[r] = fmaxf(rm[r], __shfl_xor(rm[r], msk));
#pragma unroll
    for (int r = 0; r < 4; ++r) {
      float mn = fmaxf(m2[r], rm[r]);
      fpr[r] = exp2f(m2[r] - mn);
      m2[r] = mn;
      ps[r] = 0.f;
    }
#pragma unroll
    for (int j = 0; j < 4; ++j)
#pragma unroll
      for (int r = 0; r < 4; ++r) {
        float p = exp2f(sf[j][r] - m2[r]);
        ps[r] += p;
        Ps[(w * 16 + lr + r) * 72 + j * 16 + lc] = f2bf(p);
      }
#pragma unroll
    for (int msk = 1; msk < 16; msk <<= 1)
#pragma unroll
      for (int r = 0; r < 4; ++r) ps[r] += __shfl_xor(ps[r], msk);
#pragma unroll
    for (int r = 0; r < 4; ++r) l2[r] = l2[r] * fpr[r] + ps[r];
#pragma unroll
    for (int nb = 0; nb < 8; ++nb)
#pragma unroll
      for (int r = 0; r < 4; ++r) of[nb][r] *= fpr[r];

    if (t < qt) { asm volatile("s_waitcnt vmcnt(6)" ::: "memory"); }
    else        { asm volatile("s_waitcnt vmcnt(0)" ::: "memory"); }
    asm volatile("s_waitcnt lgkmcnt(0)" ::: "memory");
    __builtin_amdgcn_s_barrier();
    __builtin_amdgcn_sched_barrier(0);

    __builtin_amdgcn_s_setprio(1);
#pragma unroll
    for (int ks = 0; ks < 2; ++ks) {
      bf16x8 ap = *(const bf16x8*)&Ps[(w * 16 + lc) * 72 + ks * 32 + ka];
#pragma unroll
      for (int nb = 0; nb < 8; ++nb) {
        int d = nb * 16 + lc;
        bf16x8 bvv = *(const bf16x8*)((const char*)Vt + d * 128 + (((ks * 4 + (lane >> 4)) ^ (d & 7)) << 4));
        of[nb] = __builtin_amdgcn_mfma_f32_16x16x32_bf16(ap, bvv, of[nb], 0, 0, 0);
      }
    }
    __builtin_amdgcn_s_setprio(0);

    asm volatile("s_waitcnt vmcnt(0)" ::: "memory");
    __builtin_amdgcn_s_barrier();
    __builtin_amdgcn_sched_barrier(0);
    cur ^= 1;
  }

#pragma unroll
  for (int r = 0; r < 4; ++r) {
    float inv = 1.f / l2[r];
    size_t m = (size_t)(bh >> 4) * 2048 + (size_t)qt * 64 + w * 16 + lr + r;
#pragma unroll
    for (int nb = 0; nb < 8; ++nb)
      o[m * 2048 + (bh & 15) * 128 + nb * 16 + lc] = f2bf(of[nb][r] * inv);
  }
}

// ---------------- launch ----------------------------------------------------
extern "C" void kernel_launch(void* const* d_in, const int* in_sizes, int n_in,
                              void* d_out, int out_size, void* d_ws, size_t ws_size,
                              hipStream_t stream) {
  const float* x = (const float*)d_in[0];
  const float* ln1w = (const float*)d_in[1];
  const float* ln1b = (const float*)d_in[2];
  const float* ln2w = (const float*)d_in[3];
  const float* ln2b = (const float*)d_in[4];
  const float* wq = (const float*)d_in[5];
  const float* bq = (const float*)d_in[6];
  const float* wdkv = (const float*)d_in[7];
  const float* bdkv = (const float*)d_in[8];
  const float* wkv = (const float*)d_in[9];
  const float* bkv = (const float*)d_in[10];
  const float* wo = (const float*)d_in[11];
  const float* bo = (const float*)d_in[12];
  const float* w1 = (const float*)d_in[13];
  const float* b1 = (const float*)d_in[14];
  const float* w2 = (const float*)d_in[15];
  const float* b2 = (const float*)d_in[16];
  (void)in_sizes; (void)n_in; (void)out_size; (void)ws_size;

  char* ws = (char*)d_ws;
  size_t off = 0;
  auto alloc = [&](size_t bytes) { void* p = ws + off; off += (bytes + 255) & ~(size_t)255; return p; };

  u16* wqT = (u16*)alloc(3072ull * 2048 * 2);
  u16* wdkvT = (u16*)alloc(640ull * 2048 * 2);   // 576 real rows, padded to 640
  u16* wkvT = (u16*)alloc(4096ull * 512 * 2);
  u16* woT = (u16*)alloc(2048ull * 2048 * 2);
  u16* w1T = (u16*)alloc(8192ull * 2048 * 2);
  u16* w2T = (u16*)alloc(2048ull * 8192 * 2);
  u16* hbuf = (u16*)alloc(4096ull * 2048 * 2);   // LN1 out; reused for LN2 out
  float* cosT = (float*)alloc(2048ull * 32 * 4);
  float* sinT = (float*)alloc(2048ull * 32 * 4);
  u16* obuf = (u16*)alloc(4096ull * 2048 * 2);
  char* G0 = ws + off;                           // FFN g overlays the region below
  u16* qallb = (u16*)alloc(32ull * 2048 * 192 * 2);
  float* qrb = (float*)alloc(4096ull * 1024 * 4);
  u16* ckvb = (u16*)alloc(4096ull * 512 * 2);
  float* krb = (float*)alloc(4096ull * 64 * 4);
  u16* krb_bf = (u16*)alloc(4096ull * 64 * 2);
  u16* knb2h = (u16*)alloc(32ull * 2048 * 128 * 2);
  u16* vb = (u16*)alloc(4096ull * 2048 * 2);
  u16* vbT = (u16*)alloc(32ull * 128 * 2048 * 2);
  u16* gb = (u16*)G0;                            // 67.1MB <= region below (~98MB)

  float* xout = (float*)d_out;                   // [4096][2048]
  float* nkv = xout + 4096ull * 2048;            // [4096][576]

  dim3 blk(256);
  dim3 blk5(512);
  k_transpose_bf16<<<dim3(64, 96), blk, 0, stream>>>(wq, wqT, 2048, 3072);
  k_transpose_bf16<<<dim3(64, 18), blk, 0, stream>>>(wdkv, wdkvT, 2048, 576);
  k_transpose_bf16<<<dim3(16, 128), blk, 0, stream>>>(wkv, wkvT, 512, 4096);
  k_transpose_bf16<<<dim3(64, 64), blk, 0, stream>>>(wo, woT, 2048, 2048);
  k_transpose_bf16<<<dim3(64, 256), blk, 0, stream>>>(w1, w1T, 2048, 8192);
  k_transpose_bf16<<<dim3(256, 64), blk, 0, stream>>>(w2, w2T, 8192, 2048);
  k_rope_table<<<dim3(256), blk, 0, stream>>>(cosT, sinT);
  k_ln<<<dim3(4096), blk, 0, stream>>>(x, ln1w, ln1b, hbuf);
  // q: M=4096 N=3072 K=2048 -> grid 12*32=384
  k_gemm2<EP_Q><<<dim3(384), blk5, 0, stream>>>(hbuf, wqT, bq, 2048, 12, 3072, qallb, qrb, nullptr);
  k_gemm<EP_DKV><<<dim3(5, 32), blk, 0, stream>>>(hbuf, wdkvT, bdkv, 2048, 576, ckvb, nkv, krb, nullptr);
  k_rope_q<<<dim3(8192), blk, 0, stream>>>(qrb, cosT, sinT, qallb);
  k_rope_k<<<dim3(512), blk, 0, stream>>>(krb, cosT, sinT, nkv, krb_bf);
  // kv: M=4096 N=4096 K=512 -> grid 16*32=512
  k_gemm2<EP_KV><<<dim3(512), blk5, 0, stream>>>(ckvb, wkvT, bkv, 512, 16, 4096, knb2h, vb, nullptr);
  k_transpose_v<<<dim3(64, 4, 32), blk, 0, stream>>>(vb, vbT);
  k_attn<<<dim3(1024), blk, 0, stream>>>(qallb, knb2h, krb_bf, vbT, obuf);
  // o: M=4096 N=2048 K=2048 -> grid 8*32=256
  k_gemm2<EP_RES><<<dim3(256), blk5, 0, stream>>>(obuf, woT, bo, 2048, 8, 2048, xout, nullptr, x);
  k_ln<<<dim3(4096), blk, 0, stream>>>(xout, ln2w, ln2b, hbuf);
  // w1: M=4096 N=8192 K=2048 -> grid 32*32=1024
  k_gemm2<EP_GELU><<<dim3(1024), blk5, 0, stream>>>(hbuf, w1T, b1, 2048, 32, 8192, gb, nullptr, nullptr);
  // w2: M=4096 N=2048 K=8192 -> grid 8*32=256
  k_gemm2<EP_RES><<<dim3(256), blk5, 0, stream>>>(gb, w2T, b2, 8192, 8, 2048, xout, nullptr, xout);
}

// Round 9
// 764.458 us; speedup vs baseline: 1.8727x; 1.0497x over previous
//
#include <hip/hip_runtime.h>
#include <hip/hip_bf16.h>

// MLA transformer block on MI355X. Round 9: k_gemm3 = 256x256 BK=64 8-wave
// schedule with depth-2 prefetch (vmcnt(8), never drained mid-loop), quadrant
// ds_read/MFMA phases + setprio, XOR swizzle. Used for q/kv/w1.

typedef short bf16x8 __attribute__((ext_vector_type(8)));
typedef float f32x4 __attribute__((ext_vector_type(4)));
typedef unsigned short u16;

#define BM 128
#define BN 128
#define BK 32

__device__ __forceinline__ u16 f2bf(float f) {
  unsigned int u = __builtin_bit_cast(unsigned int, f);
  u += 0x7FFFu + ((u >> 16) & 1u);
  return (u16)(u >> 16);
}

__device__ __forceinline__ void gload_lds16(const void* g, void* l) {
  __builtin_amdgcn_global_load_lds(
      (const __attribute__((address_space(1))) unsigned int*)(uintptr_t)g,
      (__attribute__((address_space(3))) unsigned int*)(unsigned int)(uintptr_t)l,
      16, 0, 0);
}

// ---------------- transpose + f32->bf16 : out[N][K] = (bf16) in[K][N] ------
__global__ __launch_bounds__(256) void k_transpose_bf16(
    const float* __restrict__ in, u16* __restrict__ out, int K, int N) {
  __shared__ float tile[32][33];
  int k0 = blockIdx.x * 32, n0 = blockIdx.y * 32;
  int tx = threadIdx.x & 31, ty = threadIdx.x >> 5;
#pragma unroll
  for (int i = 0; i < 4; ++i) {
    int k = k0 + ty + i * 8, n = n0 + tx;
    tile[ty + i * 8][tx] = (k < K && n < N) ? in[(size_t)k * N + n] : 0.f;
  }
  __syncthreads();
#pragma unroll
  for (int i = 0; i < 4; ++i) {
    int n = n0 + ty + i * 8, k = k0 + tx;
    if (n < N && k < K) out[(size_t)n * K + k] = f2bf(tile[tx][ty + i * 8]);
  }
}

// ---------------- V transpose per (b,h): vb[m][h*128+d] -> vbT[bh][d][s] ----
__global__ __launch_bounds__(256) void k_transpose_v(
    const u16* __restrict__ vb, u16* __restrict__ vbT) {
  __shared__ u16 tile[32][34];
  int bh = blockIdx.z, b = bh >> 4, h = bh & 15;
  int s0 = blockIdx.x * 32, d0 = blockIdx.y * 32;
  int tx = threadIdx.x & 31, ty = threadIdx.x >> 5;
#pragma unroll
  for (int i = 0; i < 4; ++i)
    tile[ty + i * 8][tx] =
        vb[((size_t)b * 2048 + s0 + ty + i * 8) * 2048 + h * 128 + d0 + tx];
  __syncthreads();
#pragma unroll
  for (int i = 0; i < 4; ++i)
    vbT[((size_t)bh * 128 + d0 + ty + i * 8) * 2048 + s0 + tx] = tile[tx][ty + i * 8];
}

// ---------------- RoPE tables: cos/sin[s][i], i<32 -------------------------
__global__ void k_rope_table(float* __restrict__ cosT, float* __restrict__ sinT) {
  int idx = blockIdx.x * 256 + threadIdx.x;
  if (idx >= 2048 * 32) return;
  int s = idx >> 5, i = idx & 31;
  float inv = exp2f(-(float)i * 0.41524101186092037f); // log2(10000)/32
  float a = (float)s * inv;
  cosT[idx] = cosf(a);
  sinT[idx] = sinf(a);
}

// ---------------- LayerNorm row=2048, out bf16 -----------------------------
__global__ __launch_bounds__(256) void k_ln(const float* __restrict__ x,
                                            const float* __restrict__ w,
                                            const float* __restrict__ b,
                                            u16* __restrict__ out) {
  const int row = blockIdx.x, tid = threadIdx.x;
  const float* xr = x + (size_t)row * 2048;
  float xv[8];
  *(float4*)&xv[0] = ((const float4*)xr)[tid * 2];
  *(float4*)&xv[4] = ((const float4*)xr)[tid * 2 + 1];
  float s = 0.f, ss = 0.f;
#pragma unroll
  for (int j = 0; j < 8; ++j) { s += xv[j]; ss += xv[j] * xv[j]; }
#pragma unroll
  for (int m_ = 32; m_; m_ >>= 1) { s += __shfl_xor(s, m_); ss += __shfl_xor(ss, m_); }
  __shared__ float red[8];
  const int wv = tid >> 6;
  if ((tid & 63) == 0) { red[wv] = s; red[wv + 4] = ss; }
  __syncthreads();
  s = red[0] + red[1] + red[2] + red[3];
  ss = red[4] + red[5] + red[6] + red[7];
  const float mean = s * (1.f / 2048.f);
  const float rs = rsqrtf(ss * (1.f / 2048.f) - mean * mean + 1e-5f);
  float wv8[8], bv8[8];
  *(float4*)&wv8[0] = ((const float4*)w)[tid * 2];
  *(float4*)&wv8[4] = ((const float4*)w)[tid * 2 + 1];
  *(float4*)&bv8[0] = ((const float4*)b)[tid * 2];
  *(float4*)&bv8[4] = ((const float4*)b)[tid * 2 + 1];
  u16 t[8] __attribute__((aligned(16)));
#pragma unroll
  for (int j = 0; j < 8; ++j) t[j] = f2bf((xv[j] - mean) * rs * wv8[j] + bv8[j]);
  *(int4*)&out[(size_t)row * 2048 + tid * 8] = *(int4*)t;
}

// ---------------- RoPE: qr f32 -> qall bf16 (cols 128..191) ----------------
__global__ void k_rope_q(const float* __restrict__ qr, const float* __restrict__ cosT,
                         const float* __restrict__ sinT, u16* __restrict__ qall) {
  int idx = blockIdx.x * 256 + threadIdx.x; // 4096*16*32
  if (idx >= 4096 * 16 * 32) return;
  int i = idx & 31, rest = idx >> 5;
  int h = rest & 15, m = rest >> 4;
  int s = m & 2047, b = m >> 11;
  float c = cosT[s * 32 + i], sn = sinT[s * 32 + i];
  const float* p = qr + (size_t)m * 1024 + h * 64 + i;
  float x0 = p[0], x1 = p[32];
  u16* q = qall + ((size_t)(b * 16 + h) * 2048 + s) * 192 + 128 + i;
  q[0] = f2bf(x0 * c - x1 * sn);
  q[32] = f2bf(x1 * c + x0 * sn);
}

// ---------------- RoPE: kr f32 -> krb_bf bf16 + nkv f32 --------------------
__global__ void k_rope_k(const float* __restrict__ kr, const float* __restrict__ cosT,
                         const float* __restrict__ sinT, float* __restrict__ nkv,
                         u16* __restrict__ krb_bf) {
  int idx = blockIdx.x * 256 + threadIdx.x; // 4096*32
  if (idx >= 4096 * 32) return;
  int i = idx & 31, m = idx >> 5;
  int s = m & 2047;
  float c = cosT[s * 32 + i], sn = sinT[s * 32 + i];
  const float* p = kr + (size_t)m * 64 + i;
  float x0 = p[0], x1 = p[32];
  float y0 = x0 * c - x1 * sn;
  float y1 = x1 * c + x0 * sn;
  nkv[(size_t)m * 576 + 512 + i] = y0;
  nkv[(size_t)m * 576 + 544 + i] = y1;
  krb_bf[(size_t)m * 64 + i] = f2bf(y0);
  krb_bf[(size_t)m * 64 + 32 + i] = f2bf(y1);
}

enum { EP_Q = 0, EP_DKV = 1, EP_KV = 2, EP_RES = 3, EP_GELU = 4 };

// ---------------- small GEMM (dkv only): m97 128x128xBK32 ------------------
template <int EP>
__global__ __launch_bounds__(256) void k_gemm(
    const u16* __restrict__ A, const u16* __restrict__ Bt,
    const float* __restrict__ bias, int K, int Nreal,
    void* out0_, void* out1_, void* out2_, const float* __restrict__ res) {
  __shared__ u16 As[BM * BK];
  __shared__ u16 Bs[BN * BK];
  const int tid = threadIdx.x;
  const int w = tid >> 6, lane = tid & 63;
  const int bm = blockIdx.y * BM, bn = blockIdx.x * BN;
  const int wr = (w >> 1) * 64, wc = (w & 1) * 64;

  const u16* Ag = A + (size_t)(bm + w * 32 + (lane >> 2)) * K + (lane & 3) * 8;
  const u16* Bg = Bt + (size_t)(bn + w * 32 + (lane >> 2)) * K + (lane & 3) * 8;
  char* lA = (char*)As + w * 2048;
  char* lB = (char*)Bs + w * 2048;

  f32x4 acc[4][4] = {};
  for (int k0 = 0; k0 < K; k0 += BK) {
    __syncthreads();
    gload_lds16(Ag, lA);
    gload_lds16(Ag + 16 * K, lA + 1024);
    gload_lds16(Bg, lB);
    gload_lds16(Bg + 16 * K, lB + 1024);
    Ag += BK; Bg += BK;
    __syncthreads();
    const int ka = (lane >> 4) * 8;
    const int lc = lane & 15;
    bf16x8 av[4], bv[4];
#pragma unroll
    for (int i = 0; i < 4; ++i) av[i] = *(const bf16x8*)&As[(wr + i * 16 + lc) * BK + ka];
#pragma unroll
    for (int j = 0; j < 4; ++j) bv[j] = *(const bf16x8*)&Bs[(wc + j * 16 + lc) * BK + ka];
#pragma unroll
    for (int i = 0; i < 4; ++i)
#pragma unroll
      for (int j = 0; j < 4; ++j)
        acc[i][j] = __builtin_amdgcn_mfma_f32_16x16x32_bf16(av[i], bv[j], acc[i][j], 0, 0, 0);
  }

  const int lr = (lane >> 4) * 4, lc = lane & 15;
#pragma unroll
  for (int i = 0; i < 4; ++i) {
#pragma unroll
    for (int j = 0; j < 4; ++j) {
      int col = bn + wc + j * 16 + lc;
      if (col >= Nreal) continue;
      float bb = bias ? bias[col] : 0.f;
#pragma unroll
      for (int r = 0; r < 4; ++r) {
        int row = bm + wr + i * 16 + lr + r;
        float c = acc[i][j][r] + bb;
        if constexpr (EP == EP_DKV) {
          u16* ckv = (u16*)out0_; float* nkv = (float*)out1_; float* kr = (float*)out2_;
          if (col < 512) { ckv[(size_t)row * 512 + col] = f2bf(c); nkv[(size_t)row * 576 + col] = c; }
          else kr[(size_t)row * 64 + (col - 512)] = c;
        }
      }
    }
  }
}

// ---------------- big GEMM v2: 128x256, BK=64, counted vmcnt (o, w2) -------
template <int EP>
__global__ __launch_bounds__(512, 2) void k_gemm2(
    const u16* __restrict__ A, const u16* __restrict__ Bt,
    const float* __restrict__ bias, int K, int gx, int Nreal,
    void* out0_, void* out1_, const float* __restrict__ res) {
  __shared__ u16 As[2][128 * 64];
  __shared__ u16 Bs[2][256 * 64];
  const int tid = threadIdx.x;
  const int w = tid >> 6, lane = tid & 63;
  const int q8 = (int)gridDim.x >> 3;
  const int u = ((int)blockIdx.x & 7) * q8 + ((int)blockIdx.x >> 3);
  const int bn = (u % gx) * 256, bm = (u / gx) * 128;
  const int wr = (w >> 2) * 64, wc = (w & 3) * 64;
  const int lc = lane & 15, hi = lane >> 4;

  const int rowid = tid >> 3;
  const int gsw = (tid & 7) ^ (rowid & 7);
  const u16* Ag = A + (size_t)(bm + rowid) * K + gsw * 8;
  const u16* Bg = Bt + (size_t)(bn + rowid) * K + gsw * 8;

  auto stage = [&](int buf, int k0) {
    char* lA = (char*)&As[buf][0] + tid * 16;
    char* lB = (char*)&Bs[buf][0] + tid * 16;
#pragma unroll
    for (int i = 0; i < 2; ++i)
      gload_lds16(Ag + (size_t)i * 64 * K + k0, lA + i * 8192);
#pragma unroll
    for (int i = 0; i < 4; ++i)
      gload_lds16(Bg + (size_t)i * 64 * K + k0, lB + i * 8192);
  };

  f32x4 acc[4][4] = {};
  const int NT = K >> 6;
  stage(0, 0);
  for (int t = 0; t < NT; ++t) {
    if (t + 1 < NT) {
      stage((t + 1) & 1, (t + 1) * 64);
      asm volatile("s_waitcnt vmcnt(6)" ::: "memory");
    } else {
      asm volatile("s_waitcnt vmcnt(0)" ::: "memory");
    }
    __builtin_amdgcn_s_barrier();
    __builtin_amdgcn_sched_barrier(0);
    const char* AsB = (const char*)&As[t & 1][0];
    const char* BsB = (const char*)&Bs[t & 1][0];
#pragma unroll
    for (int ks = 0; ks < 2; ++ks) {
      bf16x8 av[4], bv[4];
#pragma unroll
      for (int mi = 0; mi < 4; ++mi) {
        int row = wr + mi * 16 + lc;
        av[mi] = *(const bf16x8*)(AsB + row * 128 + (((ks * 4 + hi) ^ (row & 7)) << 4));
      }
#pragma unroll
      for (int ni = 0; ni < 4; ++ni) {
        int row = wc + ni * 16 + lc;
        bv[ni] = *(const bf16x8*)(BsB + row * 128 + (((ks * 4 + hi) ^ (row & 7)) << 4));
      }
#pragma unroll
      for (int mi = 0; mi < 4; ++mi)
#pragma unroll
        for (int ni = 0; ni < 4; ++ni)
          acc[mi][ni] = __builtin_amdgcn_mfma_f32_16x16x32_bf16(av[mi], bv[ni], acc[mi][ni], 0, 0, 0);
    }
    asm volatile("s_waitcnt lgkmcnt(0)" ::: "memory");
    __builtin_amdgcn_s_barrier();
  }

#pragma unroll
  for (int mi = 0; mi < 4; ++mi) {
#pragma unroll
    for (int ni = 0; ni < 4; ++ni) {
      int col = bn + wc + ni * 16 + lc;
      float bb = bias[col];
#pragma unroll
      for (int r = 0; r < 4; ++r) {
        int row = bm + wr + mi * 16 + hi * 4 + r;
        int b = row >> 11, s = row & 2047;
        float c = acc[mi][ni][r] + bb;
        if constexpr (EP == EP_Q) {
          u16* qall = (u16*)out0_; float* qr = (float*)out1_;
          int hh = col / 192, d = col - hh * 192;
          if (d < 128) qall[((size_t)(b * 16 + hh) * 2048 + s) * 192 + d] = f2bf(c);
          else qr[(size_t)row * 1024 + hh * 64 + (d - 128)] = c;
        } else if constexpr (EP == EP_KV) {
          u16* knb2h = (u16*)out0_; u16* vv = (u16*)out1_;
          int hh = col >> 8, d = col & 255;
          if (d < 128) knb2h[((size_t)(b * 16 + hh) * 2048 + s) * 128 + d] = f2bf(c);
          else vv[(size_t)row * 2048 + hh * 128 + (d - 128)] = f2bf(c);
        } else if constexpr (EP == EP_RES) {
          float* out = (float*)out0_;
          out[(size_t)row * Nreal + col] = res[(size_t)row * Nreal + col] + c;
        } else { // EP_GELU
          u16* g = (u16*)out0_;
          float gl = 0.5f * c * (1.f + erff(c * 0.70710678118f));
          g[(size_t)row * Nreal + col] = f2bf(gl);
        }
      }
    }
  }
}

// ---------------- big GEMM v3: 256x256, BK=64, depth-2 prefetch ------------
// 8 waves (2Mx4N), per-wave 128x64 output, acc[8][4]. LDS 128KB (2 buf of
// A[256][64]+B[256][64], XOR granule swizzle). Per K-step: 4 quadrant phases
// {ds_read frags -> 16 MFMA (setprio)}; then barrier, stage(s+2) into freed
// buffer, vmcnt(8) (s+2's loads stay in flight), barrier. Never drains.
template <int EP>
__global__ __launch_bounds__(512, 1) void k_gemm3(
    const u16* __restrict__ A, const u16* __restrict__ Bt,
    const float* __restrict__ bias, int K, int gx, int Nreal,
    void* out0_, void* out1_, const float* __restrict__ res) {
  __shared__ u16 As[2][256 * 64];
  __shared__ u16 Bs[2][256 * 64];
  const int tid = threadIdx.x;
  const int w = tid >> 6, lane = tid & 63;
  const int q8 = (int)gridDim.x >> 3;
  const int u = ((int)blockIdx.x & 7) * q8 + ((int)blockIdx.x >> 3);
  const int bn = (u % gx) * 256, bm = (u / gx) * 256;
  const int wm = (w >> 2) * 128, wn = (w & 3) * 64;
  const int lc = lane & 15, hi = lane >> 4;

  const int rowid = tid >> 3;                    // 0..63
  const int gsw = (tid & 7) ^ (rowid & 7);       // swizzled source granule
  const u16* Agb = A + (size_t)bm * K + gsw * 8;
  const u16* Bgb = Bt + (size_t)bn * K + gsw * 8;

  auto stage = [&](int buf, int k0) {
    char* lA = (char*)&As[buf][0] + tid * 16;
    char* lB = (char*)&Bs[buf][0] + tid * 16;
#pragma unroll
    for (int i = 0; i < 4; ++i)
      gload_lds16(Agb + (size_t)(rowid + i * 64) * K + k0, lA + i * 8192);
#pragma unroll
    for (int i = 0; i < 4; ++i)
      gload_lds16(Bgb + (size_t)(rowid + i * 64) * K + k0, lB + i * 8192);
  };

  f32x4 acc[8][4] = {};
  const int NS = K >> 6;
  stage(0, 0);
  stage(1, 64);
  asm volatile("s_waitcnt vmcnt(8)" ::: "memory");   // tile 0 landed
  __builtin_amdgcn_s_barrier();
  __builtin_amdgcn_sched_barrier(0);

  for (int s = 0; s < NS; ++s) {
    const int p = s & 1;
    const char* AsB = (const char*)&As[p][0];
    const char* BsB = (const char*)&Bs[p][0];
#pragma unroll
    for (int qa = 0; qa < 2; ++qa) {
      bf16x8 av[4][2];
#pragma unroll
      for (int mi = 0; mi < 4; ++mi) {
        int row = wm + (qa * 4 + mi) * 16 + lc;
#pragma unroll
        for (int ks = 0; ks < 2; ++ks)
          av[mi][ks] = *(const bf16x8*)(AsB + row * 128 + (((ks * 4 + hi) ^ (row & 7)) << 4));
      }
#pragma unroll
      for (int qb = 0; qb < 2; ++qb) {
        bf16x8 bv[2][2];
#pragma unroll
        for (int ni = 0; ni < 2; ++ni) {
          int row = wn + (qb * 2 + ni) * 16 + lc;
#pragma unroll
          for (int ks = 0; ks < 2; ++ks)
            bv[ni][ks] = *(const bf16x8*)(BsB + row * 128 + (((ks * 4 + hi) ^ (row & 7)) << 4));
        }
        __builtin_amdgcn_s_setprio(1);
#pragma unroll
        for (int mi = 0; mi < 4; ++mi)
#pragma unroll
          for (int ni = 0; ni < 2; ++ni)
#pragma unroll
            for (int ks = 0; ks < 2; ++ks)
              acc[qa * 4 + mi][qb * 2 + ni] = __builtin_amdgcn_mfma_f32_16x16x32_bf16(
                  av[mi][ks], bv[ni][ks], acc[qa * 4 + mi][qb * 2 + ni], 0, 0, 0);
        __builtin_amdgcn_s_setprio(0);
      }
    }
    // all reads of buf[p] complete (MFMAs consumed them); release the buffer
    __builtin_amdgcn_s_barrier();
    __builtin_amdgcn_sched_barrier(0);
    if (s + 2 < NS) {
      stage(p, (s + 2) * 64);                       // into just-freed buffer
      asm volatile("s_waitcnt vmcnt(8)" ::: "memory");  // tile s+1 landed
    } else if (s + 1 < NS) {
      asm volatile("s_waitcnt vmcnt(0)" ::: "memory");
    }
    __builtin_amdgcn_s_barrier();                   // tile s+1 visible to all
    __builtin_amdgcn_sched_barrier(0);
  }

#pragma unroll
  for (int mi = 0; mi < 8; ++mi) {
#pragma unroll
    for (int ni = 0; ni < 4; ++ni) {
      int col = bn + wn + ni * 16 + lc;
      float bb = bias[col];
#pragma unroll
      for (int r = 0; r < 4; ++r) {
        int row = bm + wm + mi * 16 + hi * 4 + r;
        int b = row >> 11, s = row & 2047;
        float c = acc[mi][ni][r] + bb;
        if constexpr (EP == EP_Q) {
          u16* qall = (u16*)out0_; float* qr = (float*)out1_;
          int hh = col / 192, d = col - hh * 192;
          if (d < 128) qall[((size_t)(b * 16 + hh) * 2048 + s) * 192 + d] = f2bf(c);
          else qr[(size_t)row * 1024 + hh * 64 + (d - 128)] = c;
        } else if constexpr (EP == EP_KV) {
          u16* knb2h = (u16*)out0_; u16* vv = (u16*)out1_;
          int hh = col >> 8, d = col & 255;
          if (d < 128) knb2h[((size_t)(b * 16 + hh) * 2048 + s) * 128 + d] = f2bf(c);
          else vv[(size_t)row * 2048 + hh * 128 + (d - 128)] = f2bf(c);
        } else if constexpr (EP == EP_RES) {
          float* out = (float*)out0_;
          out[(size_t)row * Nreal + col] = res[(size_t)row * Nreal + col] + c;
        } else { // EP_GELU
          u16* g = (u16*)out0_;
          float gl = 0.5f * c * (1.f + erff(c * 0.70710678118f));
          g[(size_t)row * Nreal + col] = f2bf(gl);
        }
      }
    }
  }
}

// ---------------- Flash attention: gload_lds staging, K dbuf, V single -----
__global__ __launch_bounds__(256) void k_attn(
    const u16* __restrict__ qall, const u16* __restrict__ knb2h,
    const u16* __restrict__ krb_bf, const u16* __restrict__ vbT,
    u16* __restrict__ o) {
  __shared__ u16 Ks[2][64 * 192];
  __shared__ u16 Vt[128 * 64];
  __shared__ u16 Ps[64 * 72];
  const int lin = blockIdx.x;
  const int qt = 31 - (lin >> 5);
  const int bh = (((lin >> 3) & 3) << 3) | (lin & 7);
  const int b = bh >> 4;
  const int tid = threadIdx.x, w = tid >> 6, lane = tid & 63;
  const float sc2 = 0.07216878365f * 1.4426950408f;
  const int lr = (lane >> 4) * 4, lc = lane & 15, ka = (lane >> 4) * 8;

  bf16x8 qf[6];
  {
    const u16* qrow = qall + ((size_t)bh * 2048 + qt * 64 + w * 16 + lc) * 192;
#pragma unroll
    for (int ks = 0; ks < 6; ++ks) qf[ks] = *(const bf16x8*)&qrow[ks * 32 + ka];
  }

  const char* kp[6];
  int kstr[6];
  {
    const char* knB = (const char*)(knb2h + (size_t)bh * 2048 * 128);
    const char* krB = (const char*)(krb_bf + (size_t)b * 2048 * 64);
#pragma unroll
    for (int i = 0; i < 6; ++i) {
      int G = (i * 4 + w) * 64 + lane;
      int row = G / 24, g = G - row * 24;
      int gs = g ^ (row & 7);
      if (gs < 16) { kp[i] = knB + row * 256 + gs * 16; kstr[i] = 16384; }
      else         { kp[i] = krB + row * 128 + (gs - 16) * 16; kstr[i] = 8192; }
    }
  }
  const char* vp[4];
  {
    const char* vB = (const char*)(vbT + (size_t)bh * 128 * 2048);
#pragma unroll
    for (int i = 0; i < 4; ++i) {
      int G = (i * 4 + w) * 64 + lane;
      int d = G >> 3, g = G & 7;
      vp[i] = vB + d * 4096 + ((g ^ (d & 7)) << 4);
    }
  }

#pragma unroll
  for (int i = 0; i < 6; ++i)
    gload_lds16(kp[i], (char*)&Ks[0][0] + (i * 4 + w) * 1024);
#pragma unroll
  for (int i = 0; i < 6; ++i) kp[i] += kstr[i];
  asm volatile("s_waitcnt vmcnt(0)" ::: "memory");
  __builtin_amdgcn_s_barrier();
  __builtin_amdgcn_sched_barrier(0);

  float m2[4] = {-1e30f, -1e30f, -1e30f, -1e30f};
  float l2[4] = {0.f, 0.f, 0.f, 0.f};
  f32x4 of[8] = {};
  int cur = 0;

  for (int t = 0; t <= qt; ++t) {
#pragma unroll
    for (int i = 0; i < 4; ++i)
      gload_lds16(vp[i], (char*)Vt + (i * 4 + w) * 1024);
#pragma unroll
    for (int i = 0; i < 4; ++i) vp[i] += 128;
    __builtin_amdgcn_sched_barrier(0);
    if (t < qt) {
      char* kd = (char*)&Ks[cur ^ 1][0];
#pragma unroll
      for (int i = 0; i < 6; ++i)
        gload_lds16(kp[i], kd + (i * 4 + w) * 1024);
#pragma unroll
      for (int i = 0; i < 6; ++i) kp[i] += kstr[i];
    }
    __builtin_amdgcn_sched_barrier(0);

    const char* KsL = (const char*)&Ks[cur][0];
    f32x4 sf[4] = {};
    __builtin_amdgcn_s_setprio(1);
#pragma unroll
    for (int j = 0; j < 4; ++j) {
#pragma unroll
      for (int ks = 0; ks < 6; ++ks) {
        int row = j * 16 + lc;
        bf16x8 kf = *(const bf16x8*)(KsL + row * 384 + (((ks * 4 + (lane >> 4)) ^ (row & 7)) << 4));
        sf[j] = __builtin_amdgcn_mfma_f32_16x16x32_bf16(qf[ks], kf, sf[j], 0, 0, 0);
      }
    }
    __builtin_amdgcn_s_setprio(0);

    float rm[4], fpr[4], ps[4];
#pragma unroll
    for (int j = 0; j < 4; ++j)
#pragma unroll
      for (int r = 0; r < 4; ++r) {
        float x_ = sf[j][r] * sc2;
        if (t == qt) {
          int colg = t * 64 + j * 16 + lc;
          int rowg = qt * 64 + w * 16 + lr + r;
          if (colg > rowg) x_ = -1e30f;
        }
        sf[j][r] = x_;
      }
#pragma unroll
    for (int r = 0; r < 4; ++r)
      rm[r] = fmaxf(fmaxf(sf[0][r], sf[1][r]), fmaxf(sf[2][r], sf[3][r]));
#pragma unroll
    for (int msk = 1; msk < 16; msk <<= 1)
#pragma unroll
      for (int r = 0; r < 4; ++r) rm[r] = fmaxf(rm[r], __shfl_xor(rm[r], msk));
#pragma unroll
    for (int r = 0; r < 4; ++r) {
      float mn = fmaxf(m2[r], rm[r]);
      fpr[r] = exp2f(m2[r] - mn);
      m2[r] = mn;
      ps[r] = 0.f;
    }
#pragma unroll
    for (int j = 0; j < 4; ++j)
#pragma unroll
      for (int r = 0; r < 4; ++r) {
        float p = exp2f(sf[j][r] - m2[r]);
        ps[r] += p;
        Ps[(w * 16 + lr + r) * 72 + j * 16 + lc] = f2bf(p);
      }
#pragma unroll
    for (int msk = 1; msk < 16; msk <<= 1)
#pragma unroll
      for (int r = 0; r < 4; ++r) ps[r] += __shfl_xor(ps[r], msk);
#pragma unroll
    for (int r = 0; r < 4; ++r) l2[r] = l2[r] * fpr[r] + ps[r];
#pragma unroll
    for (int nb = 0; nb < 8; ++nb)
#pragma unroll
      for (int r = 0; r < 4; ++r) of[nb][r] *= fpr[r];

    if (t < qt) { asm volatile("s_waitcnt vmcnt(6)" ::: "memory"); }
    else        { asm volatile("s_waitcnt vmcnt(0)" ::: "memory"); }
    asm volatile("s_waitcnt lgkmcnt(0)" ::: "memory");
    __builtin_amdgcn_s_barrier();
    __builtin_amdgcn_sched_barrier(0);

    __builtin_amdgcn_s_setprio(1);
#pragma unroll
    for (int ks = 0; ks < 2; ++ks) {
      bf16x8 ap = *(const bf16x8*)&Ps[(w * 16 + lc) * 72 + ks * 32 + ka];
#pragma unroll
      for (int nb = 0; nb < 8; ++nb) {
        int d = nb * 16 + lc;
        bf16x8 bvv = *(const bf16x8*)((const char*)Vt + d * 128 + (((ks * 4 + (lane >> 4)) ^ (d & 7)) << 4));
        of[nb] = __builtin_amdgcn_mfma_f32_16x16x32_bf16(ap, bvv, of[nb], 0, 0, 0);
      }
    }
    __builtin_amdgcn_s_setprio(0);

    asm volatile("s_waitcnt vmcnt(0)" ::: "memory");
    __builtin_amdgcn_s_barrier();
    __builtin_amdgcn_sched_barrier(0);
    cur ^= 1;
  }

#pragma unroll
  for (int r = 0; r < 4; ++r) {
    float inv = 1.f / l2[r];
    size_t m = (size_t)(bh >> 4) * 2048 + (size_t)qt * 64 + w * 16 + lr + r;
#pragma unroll
    for (int nb = 0; nb < 8; ++nb)
      o[m * 2048 + (bh & 15) * 128 + nb * 16 + lc] = f2bf(of[nb][r] * inv);
  }
}

// ---------------- launch ----------------------------------------------------
extern "C" void kernel_launch(void* const* d_in, const int* in_sizes, int n_in,
                              void* d_out, int out_size, void* d_ws, size_t ws_size,
                              hipStream_t stream) {
  const float* x = (const float*)d_in[0];
  const float* ln1w = (const float*)d_in[1];
  const float* ln1b = (const float*)d_in[2];
  const float* ln2w = (const float*)d_in[3];
  const float* ln2b = (const float*)d_in[4];
  const float* wq = (const float*)d_in[5];
  const float* bq = (const float*)d_in[6];
  const float* wdkv = (const float*)d_in[7];
  const float* bdkv = (const float*)d_in[8];
  const float* wkv = (const float*)d_in[9];
  const float* bkv = (const float*)d_in[10];
  const float* wo = (const float*)d_in[11];
  const float* bo = (const float*)d_in[12];
  const float* w1 = (const float*)d_in[13];
  const float* b1 = (const float*)d_in[14];
  const float* w2 = (const float*)d_in[15];
  const float* b2 = (const float*)d_in[16];
  (void)in_sizes; (void)n_in; (void)out_size; (void)ws_size;

  char* ws = (char*)d_ws;
  size_t off = 0;
  auto alloc = [&](size_t bytes) { void* p = ws + off; off += (bytes + 255) & ~(size_t)255; return p; };

  u16* wqT = (u16*)alloc(3072ull * 2048 * 2);
  u16* wdkvT = (u16*)alloc(640ull * 2048 * 2);   // 576 real rows, padded to 640
  u16* wkvT = (u16*)alloc(4096ull * 512 * 2);
  u16* woT = (u16*)alloc(2048ull * 2048 * 2);
  u16* w1T = (u16*)alloc(8192ull * 2048 * 2);
  u16* w2T = (u16*)alloc(2048ull * 8192 * 2);
  u16* hbuf = (u16*)alloc(4096ull * 2048 * 2);   // LN1 out; reused for LN2 out
  float* cosT = (float*)alloc(2048ull * 32 * 4);
  float* sinT = (float*)alloc(2048ull * 32 * 4);
  u16* obuf = (u16*)alloc(4096ull * 2048 * 2);
  char* G0 = ws + off;                           // FFN g overlays the region below
  u16* qallb = (u16*)alloc(32ull * 2048 * 192 * 2);
  float* qrb = (float*)alloc(4096ull * 1024 * 4);
  u16* ckvb = (u16*)alloc(4096ull * 512 * 2);
  float* krb = (float*)alloc(4096ull * 64 * 4);
  u16* krb_bf = (u16*)alloc(4096ull * 64 * 2);
  u16* knb2h = (u16*)alloc(32ull * 2048 * 128 * 2);
  u16* vb = (u16*)alloc(4096ull * 2048 * 2);
  u16* vbT = (u16*)alloc(32ull * 128 * 2048 * 2);
  u16* gb = (u16*)G0;                            // 67.1MB <= region below (~98MB)

  float* xout = (float*)d_out;                   // [4096][2048]
  float* nkv = xout + 4096ull * 2048;            // [4096][576]

  dim3 blk(256);
  dim3 blk5(512);
  k_transpose_bf16<<<dim3(64, 96), blk, 0, stream>>>(wq, wqT, 2048, 3072);
  k_transpose_bf16<<<dim3(64, 18), blk, 0, stream>>>(wdkv, wdkvT, 2048, 576);
  k_transpose_bf16<<<dim3(16, 128), blk, 0, stream>>>(wkv, wkvT, 512, 4096);
  k_transpose_bf16<<<dim3(64, 64), blk, 0, stream>>>(wo, woT, 2048, 2048);
  k_transpose_bf16<<<dim3(64, 256), blk, 0, stream>>>(w1, w1T, 2048, 8192);
  k_transpose_bf16<<<dim3(256, 64), blk, 0, stream>>>(w2, w2T, 8192, 2048);
  k_rope_table<<<dim3(256), blk, 0, stream>>>(cosT, sinT);
  k_ln<<<dim3(4096), blk, 0, stream>>>(x, ln1w, ln1b, hbuf);
  // q: M=4096 N=3072 K=2048 -> 256^2 tiles: 12*16=192
  k_gemm3<EP_Q><<<dim3(192), blk5, 0, stream>>>(hbuf, wqT, bq, 2048, 12, 3072, qallb, qrb, nullptr);
  k_gemm<EP_DKV><<<dim3(5, 32), blk, 0, stream>>>(hbuf, wdkvT, bdkv, 2048, 576, ckvb, nkv, krb, nullptr);
  k_rope_q<<<dim3(8192), blk, 0, stream>>>(qrb, cosT, sinT, qallb);
  k_rope_k<<<dim3(512), blk, 0, stream>>>(krb, cosT, sinT, nkv, krb_bf);
  // kv: M=4096 N=4096 K=512 -> 16*16=256
  k_gemm3<EP_KV><<<dim3(256), blk5, 0, stream>>>(ckvb, wkvT, bkv, 512, 16, 4096, knb2h, vb, nullptr);
  k_transpose_v<<<dim3(64, 4, 32), blk, 0, stream>>>(vb, vbT);
  k_attn<<<dim3(1024), blk, 0, stream>>>(qallb, knb2h, krb_bf, vbT, obuf);
  // o: M=4096 N=2048 K=2048 -> gemm2 grid 8*32=256 (fills chip)
  k_gemm2<EP_RES><<<dim3(256), blk5, 0, stream>>>(obuf, woT, bo, 2048, 8, 2048, xout, nullptr, x);
  k_ln<<<dim3(4096), blk, 0, stream>>>(xout, ln2w, ln2b, hbuf);
  // w1: M=4096 N=8192 K=2048 -> 32*16=512
  k_gemm3<EP_GELU><<<dim3(512), blk5, 0, stream>>>(hbuf, w1T, b1, 2048, 32, 8192, gb, nullptr, nullptr);
  // w2: M=4096 N=2048 K=8192 -> gemm2 grid 8*32=256 (fills chip)
  k_gemm2<EP_RES><<<dim3(256), blk5, 0, stream>>>(gb, w2T, b2, 8192, 8, 2048, xout, nullptr, xout);
}